// Round 1
// baseline (452.368 us; speedup 1.0000x reference)
//
#include <hip/hip_runtime.h>

constexpr int NB = 16, NN = 1024, NF = 512, NK = 128;
constexpr float EPSV = 1e-15f;

// -------- build inverse row map: row_of[flat_index[t]] = t --------
__global__ __launch_bounds__(256) void k_build_rowof(const int* __restrict__ fidx,
                                                     int* __restrict__ rowof, int T) {
  int t = blockIdx.x * 256 + threadIdx.x;
  if (t < T) rowof[fidx[t]] = t;
}

// -------- softmax each valid row of s, scatter into dense sm --------
__global__ __launch_bounds__(256) void k_softmax(const float* __restrict__ s,
                                                 const int* __restrict__ fidx,
                                                 float* __restrict__ sm, int T) {
  int t = blockIdx.x * 4 + (threadIdx.x >> 6);
  if (t >= T) return;
  int lane = threadIdx.x & 63;
  const float* row = s + (size_t)t * NK;
  float a = row[lane], b2 = row[lane + 64];
  float m = fmaxf(a, b2);
#pragma unroll
  for (int off = 32; off; off >>= 1) m = fmaxf(m, __shfl_xor(m, off, 64));
  float e0 = expf(a - m), e1 = expf(b2 - m);
  float ssum = e0 + e1;
#pragma unroll
  for (int off = 32; off; off >>= 1) ssum += __shfl_xor(ssum, off, 64);
  float inv = 1.0f / ssum;
  float* orow = sm + (size_t)fidx[t] * NK;
  orow[lane] = e0 * inv;
  orow[lane + 64] = e1 * inv;
}

// -------- Y[b] = adj[b] @ sm[b]  (N x K), fused d_flat = rowsum(adj) --------
// grid (N/64, B), 256 threads, 64x128 tile, micro 4x8
__global__ __launch_bounds__(256) void k_adj_sm(const float* __restrict__ adj,
                                                const float* __restrict__ sm,
                                                float* __restrict__ Y,
                                                float* __restrict__ dflat) {
  __shared__ float As[64][68];   // [m_local][n_local], +4 pad keeps 16B align, spreads banks
  __shared__ float Ss[64][128];  // [m_local][k]
  int b = blockIdx.y;
  int n0 = blockIdx.x * 64;
  const float* A = adj + (size_t)b * NN * NN;
  const float* S = sm + (size_t)b * NN * NK;
  int tid = threadIdx.x;
  int tr = tid >> 4, tc = tid & 15;
  int r0 = tr * 4, c0 = tc * 8;
  float acc[4][8] = {};
  float rsum[4] = {0.f, 0.f, 0.f, 0.f};
  for (int m0 = 0; m0 < NN; m0 += 64) {
    __syncthreads();
    // A tile 64x64, stored transposed; fuse row-sum via 16-lane shuffle reduce
#pragma unroll
    for (int p = 0; p < 4; ++p) {
      int r = p * 16 + tr;
      float4 v = *(const float4*)(A + (size_t)(n0 + r) * NN + m0 + tc * 4);
      As[tc * 4 + 0][r] = v.x; As[tc * 4 + 1][r] = v.y;
      As[tc * 4 + 2][r] = v.z; As[tc * 4 + 3][r] = v.w;
      float ps = v.x + v.y + v.z + v.w;
      ps += __shfl_xor(ps, 1, 64); ps += __shfl_xor(ps, 2, 64);
      ps += __shfl_xor(ps, 4, 64); ps += __shfl_xor(ps, 8, 64);
      rsum[p] += ps;
    }
    // sm tile 64x128
#pragma unroll
    for (int p = 0; p < 8; ++p) {
      int r = p * 8 + (tid >> 5);
      int c = (tid & 31) * 4;
      *(float4*)&Ss[r][c] = *(const float4*)(S + (size_t)(m0 + r) * NK + c);
    }
    __syncthreads();
#pragma unroll
    for (int mm = 0; mm < 64; ++mm) {
      float a[4], bb[8];
      *(float4*)a = *(const float4*)&As[mm][r0];
      *(float4*)&bb[0] = *(const float4*)&Ss[mm][c0];
      *(float4*)&bb[4] = *(const float4*)&Ss[mm][c0 + 4];
#pragma unroll
      for (int i = 0; i < 4; ++i)
#pragma unroll
        for (int j = 0; j < 8; ++j)
          acc[i][j] = fmaf(a[i], bb[j], acc[i][j]);
    }
  }
  float* Yb = Y + (size_t)b * NN * NK;
#pragma unroll
  for (int i = 0; i < 4; ++i) {
    *(float4*)(Yb + (size_t)(n0 + r0 + i) * NK + c0) = *(float4*)&acc[i][0];
    *(float4*)(Yb + (size_t)(n0 + r0 + i) * NK + c0 + 4) = *(float4*)&acc[i][4];
  }
  if (tc == 0) {
#pragma unroll
    for (int p = 0; p < 4; ++p) dflat[b * NN + n0 + p * 16 + tr] = rsum[p];
  }
}

// -------- out[b] = sm[b]^T @ x_gathered[b]  (K x F) --------
// grid (F/32, B), 256 threads, 128x32 tile, micro 4x4
__global__ __launch_bounds__(256) void k_feat(const float* __restrict__ sm,
                                              const float* __restrict__ x,
                                              const int* __restrict__ rowof,
                                              float* __restrict__ outf) {
  __shared__ float Ss[64][128];
  __shared__ float Xs[64][36];
  int b = blockIdx.y;
  int f0 = blockIdx.x * 32;
  const float* S = sm + (size_t)b * NN * NK;
  int tid = threadIdx.x;
  int k0 = (tid & 31) * 4;
  int fl = (tid >> 5) * 4;
  float acc[4][4] = {};
  for (int n0 = 0; n0 < NN; n0 += 64) {
    __syncthreads();
#pragma unroll
    for (int p = 0; p < 8; ++p) {
      int r = p * 8 + (tid >> 5);
      int c = (tid & 31) * 4;
      *(float4*)&Ss[r][c] = *(const float4*)(S + (size_t)(n0 + r) * NK + c);
    }
#pragma unroll
    for (int p = 0; p < 2; ++p) {
      int r = p * 32 + (tid >> 3);
      int c = (tid & 7) * 4;
      int ri = rowof[b * NN + n0 + r];
      float4 v = make_float4(0.f, 0.f, 0.f, 0.f);
      if (ri >= 0) v = *(const float4*)(x + (size_t)ri * NF + f0 + c);
      *(float4*)&Xs[r][c] = v;
    }
    __syncthreads();
#pragma unroll
    for (int nn = 0; nn < 64; ++nn) {
      float a[4], bb[4];
      *(float4*)a = *(const float4*)&Ss[nn][k0];
      *(float4*)bb = *(const float4*)&Xs[nn][fl];
#pragma unroll
      for (int i = 0; i < 4; ++i)
#pragma unroll
        for (int j = 0; j < 4; ++j)
          acc[i][j] = fmaf(a[i], bb[j], acc[i][j]);
    }
  }
  float* O = outf + (size_t)b * NK * NF;
#pragma unroll
  for (int i = 0; i < 4; ++i)
    *(float4*)(O + (size_t)(k0 + i) * NF + f0 + fl) = *(float4*)&acc[i][0];
}

// -------- partials: adjraw += sm^T Y, ss += sm^T sm  (K x K each) --------
// grid (8 chunks, B, 2), 256 threads, micro 8x8, atomic accumulate
__global__ __launch_bounds__(256) void k_tt(const float* __restrict__ sm,
                                            const float* __restrict__ Y,
                                            float* __restrict__ adjraw,
                                            float* __restrict__ ssb) {
  __shared__ float Ls[32][128];
  __shared__ float Rs[32][128];
  int b = blockIdx.y;
  int nbase = blockIdx.x * 128;
  int z = blockIdx.z;
  const float* L = sm + (size_t)b * NN * NK;
  const float* R = (z ? sm : Y) + (size_t)b * NN * NK;
  float* O = (z ? ssb : adjraw) + (size_t)b * NK * NK;
  int tid = threadIdx.x;
  int k0 = (tid >> 4) * 8, c0 = (tid & 15) * 8;
  float acc[8][8] = {};
  for (int n0 = 0; n0 < 128; n0 += 32) {
    __syncthreads();
    int lr = tid >> 3, lc = (tid & 7) * 16;
    const float* Lp = L + (size_t)(nbase + n0 + lr) * NK + lc;
    const float* Rp = R + (size_t)(nbase + n0 + lr) * NK + lc;
#pragma unroll
    for (int j = 0; j < 4; ++j) {
      *(float4*)&Ls[lr][lc + j * 4] = *(const float4*)(Lp + j * 4);
      *(float4*)&Rs[lr][lc + j * 4] = *(const float4*)(Rp + j * 4);
    }
    __syncthreads();
#pragma unroll
    for (int nn = 0; nn < 32; ++nn) {
      float a[8], bb[8];
      *(float4*)&a[0] = *(const float4*)&Ls[nn][k0];
      *(float4*)&a[4] = *(const float4*)&Ls[nn][k0 + 4];
      *(float4*)&bb[0] = *(const float4*)&Rs[nn][c0];
      *(float4*)&bb[4] = *(const float4*)&Rs[nn][c0 + 4];
#pragma unroll
      for (int i = 0; i < 8; ++i)
#pragma unroll
        for (int j = 0; j < 8; ++j)
          acc[i][j] = fmaf(a[i], bb[j], acc[i][j]);
    }
  }
#pragma unroll
  for (int i = 0; i < 8; ++i)
#pragma unroll
    for (int j = 0; j < 8; ++j)
      atomicAdd(&O[(size_t)(k0 + i) * NK + c0 + j], acc[i][j]);
}

__device__ __forceinline__ float block_reduce_sum(float v, float* red) {
  int tid = threadIdx.x;
  red[tid] = v;
  __syncthreads();
#pragma unroll
  for (int sft = 128; sft; sft >>= 1) {
    if (tid < sft) red[tid] += red[tid + sft];
    __syncthreads();
  }
  float r = red[0];
  __syncthreads();
  return r;
}

// -------- per-batch epilogue: losses + degree-normalized out_adj --------
__global__ __launch_bounds__(256) void k_finalize(const float* __restrict__ sm,
                                                  const float* __restrict__ dflat,
                                                  const float* __restrict__ adjraw,
                                                  const float* __restrict__ ssb,
                                                  float* __restrict__ out_adj,
                                                  float* __restrict__ out_loss) {
  __shared__ float red[256];
  __shared__ float sd[NK];
  int b = blockIdx.x, tid = threadIdx.x;
  const float* AR = adjraw + (size_t)b * NK * NK;
  const float* SS = ssb + (size_t)b * NK * NK;
  const float* S = sm + (size_t)b * NN * NK;

  // mincut numerator = trace(sm^T A sm)
  float tv = (tid < NK) ? AR[tid * NK + tid] : 0.f;
  float trace = block_reduce_sum(tv, red);

  // mincut denominator = sum_n d_flat[n] * ||sm[n,:]||^2
  float den = 0.f;
  for (int i4 = tid; i4 < NN * NK / 4; i4 += 256) {
    float4 v = *(const float4*)(S + (size_t)i4 * 4);
    int n = i4 >> 5;  // (i4*4)/128
    den += dflat[b * NN + n] * (v.x * v.x + v.y * v.y + v.z * v.z + v.w * v.w);
  }
  den = block_reduce_sum(den, red);

  // ||ss||_F
  float n2 = 0.f;
  for (int i4 = tid; i4 < NK * NK / 4; i4 += 256) {
    float4 v = *(const float4*)(SS + (size_t)i4 * 4);
    n2 += v.x * v.x + v.y * v.y + v.z * v.z + v.w * v.w;
  }
  float nrm = sqrtf(block_reduce_sum(n2, red));

  // ortho = || ss/||ss|| - I/sqrt(K) ||_F
  const float isk = 0.08838834764831845f;  // 1/sqrt(128)
  float osum = 0.f;
  for (int i = tid; i < NK * NK; i += 256) {
    int r = i >> 7, c = i & (NK - 1);
    float val = SS[i] / nrm - ((r == c) ? isk : 0.f);
    osum += val * val;
  }
  float ortho = sqrtf(block_reduce_sum(osum, red));

  // zero-diag row sums -> d
  if (tid < NK) {
    float rsumv = 0.f;
    const float* row = AR + (size_t)tid * NK;
    for (int j = 0; j < NK; ++j) rsumv += (j == tid) ? 0.f : row[j];
    sd[tid] = sqrtf(rsumv) + EPSV;
  }
  __syncthreads();

  float* OA = out_adj + (size_t)b * NK * NK;
  for (int i = tid; i < NK * NK; i += 256) {
    int r = i >> 7, c = i & (NK - 1);
    OA[i] = (r == c) ? 0.f : AR[i] / (sd[r] * sd[c]);
  }

  if (tid == 0) {
    atomicAdd(&out_loss[0], -(trace / den) * (1.0f / NB));
    atomicAdd(&out_loss[1], ortho * (1.0f / NB));
  }
}

extern "C" void kernel_launch(void* const* d_in, const int* in_sizes, int n_in,
                              void* d_out, int out_size, void* d_ws, size_t ws_size,
                              hipStream_t stream) {
  const float* x = (const float*)d_in[0];
  const float* s = (const float*)d_in[1];
  const float* adj = (const float*)d_in[2];
  const int* fidx = (const int*)d_in[3];
  int T = in_sizes[3];

  // output layout: sm | out | out_adj | mincut_loss | ortho_loss
  float* out_sm = (float*)d_out;
  float* out_feat = out_sm + (size_t)NB * NN * NK;
  float* out_adj = out_feat + (size_t)NB * NK * NF;
  float* out_loss = out_adj + (size_t)NB * NK * NK;

  // workspace layout
  float* Y = (float*)d_ws;                         // B*N*K
  float* dflat = Y + (size_t)NB * NN * NK;         // B*N
  float* adjraw = dflat + (size_t)NB * NN;         // B*K*K
  float* ssb = adjraw + (size_t)NB * NK * NK;      // B*K*K
  int* rowof = (int*)(ssb + (size_t)NB * NK * NK); // B*N ints

  hipMemsetAsync(out_sm, 0, (size_t)NB * NN * NK * sizeof(float), stream);
  hipMemsetAsync(out_loss, 0, 2 * sizeof(float), stream);
  hipMemsetAsync(adjraw, 0, (size_t)2 * NB * NK * NK * sizeof(float), stream);
  hipMemsetAsync(rowof, 0xFF, (size_t)NB * NN * sizeof(int), stream);

  k_build_rowof<<<(T + 255) / 256, 256, 0, stream>>>(fidx, rowof, T);
  k_softmax<<<(T + 3) / 4, 256, 0, stream>>>(s, fidx, out_sm, T);
  k_adj_sm<<<dim3(NN / 64, NB), 256, 0, stream>>>(adj, out_sm, Y, dflat);
  k_feat<<<dim3(NF / 32, NB), 256, 0, stream>>>(out_sm, x, rowof, out_feat);
  k_tt<<<dim3(8, NB, 2), 256, 0, stream>>>(out_sm, Y, adjraw, ssb);
  k_finalize<<<NB, 256, 0, stream>>>(out_sm, dflat, adjraw, ssb, out_adj, out_loss);
}

// Round 2
// 323.405 us; speedup vs baseline: 1.3988x; 1.3988x over previous
//
#include <hip/hip_runtime.h>

constexpr int NB = 16, NN = 1024, NF = 512, NK = 128;
constexpr int NCH = 8;  // k_tt row chunks (128 rows each)
constexpr float EPSV = 1e-15f;

// -------- build inverse row map: row_of[flat_index[t]] = t --------
__global__ __launch_bounds__(256) void k_build_rowof(const int* __restrict__ fidx,
                                                     int* __restrict__ rowof, int T) {
  int t = blockIdx.x * 256 + threadIdx.x;
  if (t < T) rowof[fidx[t]] = t;
}

// -------- softmax each valid row of s, scatter into dense sm --------
__global__ __launch_bounds__(256) void k_softmax(const float* __restrict__ s,
                                                 const int* __restrict__ fidx,
                                                 float* __restrict__ sm, int T) {
  int t = blockIdx.x * 4 + (threadIdx.x >> 6);
  if (t >= T) return;
  int lane = threadIdx.x & 63;
  const float* row = s + (size_t)t * NK;
  float a = row[lane], b2 = row[lane + 64];
  float m = fmaxf(a, b2);
#pragma unroll
  for (int off = 32; off; off >>= 1) m = fmaxf(m, __shfl_xor(m, off, 64));
  float e0 = expf(a - m), e1 = expf(b2 - m);
  float ssum = e0 + e1;
#pragma unroll
  for (int off = 32; off; off >>= 1) ssum += __shfl_xor(ssum, off, 64);
  float inv = 1.0f / ssum;
  float* orow = sm + (size_t)fidx[t] * NK;
  orow[lane] = e0 * inv;
  orow[lane + 64] = e1 * inv;
}

// -------- Y[b] = adj[b] @ sm[b]  (N x K), fused d_flat = rowsum(adj) --------
// grid (N/64, B), 256 threads, 64x128 tile, micro 4x8
__global__ __launch_bounds__(256) void k_adj_sm(const float* __restrict__ adj,
                                                const float* __restrict__ sm,
                                                float* __restrict__ Y,
                                                float* __restrict__ dflat) {
  __shared__ float As[64][68];   // [m_local][n_local] transposed
  __shared__ float Ss[64][128];  // [m_local][k]
  int b = blockIdx.y;
  int n0 = blockIdx.x * 64;
  const float* A = adj + (size_t)b * NN * NN;
  const float* S = sm + (size_t)b * NN * NK;
  int tid = threadIdx.x;
  int tr = tid >> 4, tc = tid & 15;
  int r0 = tr * 4, c0 = tc * 8;
  float acc[4][8] = {};
  float rsum[4] = {0.f, 0.f, 0.f, 0.f};
  for (int m0 = 0; m0 < NN; m0 += 64) {
    __syncthreads();
    // A tile 64x64, stored transposed; fuse row-sum via 16-lane shuffle reduce
#pragma unroll
    for (int p = 0; p < 4; ++p) {
      int r = p * 16 + tr;
      float4 v = *(const float4*)(A + (size_t)(n0 + r) * NN + m0 + tc * 4);
      As[tc * 4 + 0][r] = v.x; As[tc * 4 + 1][r] = v.y;
      As[tc * 4 + 2][r] = v.z; As[tc * 4 + 3][r] = v.w;
      float ps = v.x + v.y + v.z + v.w;
      ps += __shfl_xor(ps, 1, 64); ps += __shfl_xor(ps, 2, 64);
      ps += __shfl_xor(ps, 4, 64); ps += __shfl_xor(ps, 8, 64);
      rsum[p] += ps;
    }
    // sm tile 64x128
#pragma unroll
    for (int p = 0; p < 8; ++p) {
      int r = p * 8 + (tid >> 5);
      int c = (tid & 31) * 4;
      *(float4*)&Ss[r][c] = *(const float4*)(S + (size_t)(m0 + r) * NK + c);
    }
    __syncthreads();
#pragma unroll
    for (int mm = 0; mm < 64; ++mm) {
      float a[4], bb[8];
      *(float4*)a = *(const float4*)&As[mm][r0];
      *(float4*)&bb[0] = *(const float4*)&Ss[mm][c0];
      *(float4*)&bb[4] = *(const float4*)&Ss[mm][c0 + 4];
#pragma unroll
      for (int i = 0; i < 4; ++i)
#pragma unroll
        for (int j = 0; j < 8; ++j)
          acc[i][j] = fmaf(a[i], bb[j], acc[i][j]);
    }
  }
  float* Yb = Y + (size_t)b * NN * NK;
#pragma unroll
  for (int i = 0; i < 4; ++i) {
    *(float4*)(Yb + (size_t)(n0 + r0 + i) * NK + c0) = *(float4*)&acc[i][0];
    *(float4*)(Yb + (size_t)(n0 + r0 + i) * NK + c0 + 4) = *(float4*)&acc[i][4];
  }
  if (tc == 0) {
#pragma unroll
    for (int p = 0; p < 4; ++p) dflat[b * NN + n0 + p * 16 + tr] = rsum[p];
  }
}

// -------- out[b] = sm[b]^T @ x_gathered[b]  (K x F) --------
__global__ __launch_bounds__(256) void k_feat(const float* __restrict__ sm,
                                              const float* __restrict__ x,
                                              const int* __restrict__ rowof,
                                              float* __restrict__ outf) {
  __shared__ float Ss[64][128];
  __shared__ float Xs[64][36];
  int b = blockIdx.y;
  int f0 = blockIdx.x * 32;
  const float* S = sm + (size_t)b * NN * NK;
  int tid = threadIdx.x;
  int k0 = (tid & 31) * 4;
  int fl = (tid >> 5) * 4;
  float acc[4][4] = {};
  for (int n0 = 0; n0 < NN; n0 += 64) {
    __syncthreads();
#pragma unroll
    for (int p = 0; p < 8; ++p) {
      int r = p * 8 + (tid >> 5);
      int c = (tid & 31) * 4;
      *(float4*)&Ss[r][c] = *(const float4*)(S + (size_t)(n0 + r) * NK + c);
    }
#pragma unroll
    for (int p = 0; p < 2; ++p) {
      int r = p * 32 + (tid >> 3);
      int c = (tid & 7) * 4;
      int ri = rowof[b * NN + n0 + r];
      float4 v = make_float4(0.f, 0.f, 0.f, 0.f);
      if (ri >= 0) v = *(const float4*)(x + (size_t)ri * NF + f0 + c);
      *(float4*)&Xs[r][c] = v;
    }
    __syncthreads();
#pragma unroll
    for (int nn = 0; nn < 64; ++nn) {
      float a[4], bb[4];
      *(float4*)a = *(const float4*)&Ss[nn][k0];
      *(float4*)bb = *(const float4*)&Xs[nn][fl];
#pragma unroll
      for (int i = 0; i < 4; ++i)
#pragma unroll
        for (int j = 0; j < 4; ++j)
          acc[i][j] = fmaf(a[i], bb[j], acc[i][j]);
    }
  }
  float* O = outf + (size_t)b * NK * NF;
#pragma unroll
  for (int i = 0; i < 4; ++i)
    *(float4*)(O + (size_t)(k0 + i) * NF + f0 + fl) = *(float4*)&acc[i][0];
}

__device__ __forceinline__ float block_reduce_sum(float v, float* red) {
  int tid = threadIdx.x;
  red[tid] = v;
  __syncthreads();
#pragma unroll
  for (int sft = 128; sft; sft >>= 1) {
    if (tid < sft) red[tid] += red[tid + sft];
    __syncthreads();
  }
  float r = red[0];
  __syncthreads();
  return r;
}

// -------- partials: padj[ch][b] = sm_ch^T Y_ch, pss[ch][b] = sm_ch^T sm_ch --------
// NO atomics: direct per-chunk partial stores. Fused mincut-den partial (z=1).
// grid (NCH, B, 2), 256 threads, micro 8x8
__global__ __launch_bounds__(256) void k_tt(const float* __restrict__ sm,
                                            const float* __restrict__ Y,
                                            const float* __restrict__ dflat,
                                            float* __restrict__ padj,
                                            float* __restrict__ pss,
                                            float* __restrict__ denb) {
  __shared__ float Ls[32][128];
  __shared__ float Rs[32][128];
  __shared__ float red[256];
  int ch = blockIdx.x, b = blockIdx.y, z = blockIdx.z;
  int nbase = ch * 128;
  const float* L = sm + (size_t)b * NN * NK;
  const float* R = (z ? sm : Y) + (size_t)b * NN * NK;
  float* O = (z ? pss : padj) + ((size_t)ch * NB + b) * NK * NK;
  int tid = threadIdx.x;
  int k0 = (tid >> 4) * 8, c0 = (tid & 15) * 8;
  int lr = tid >> 3, lc = (tid & 7) * 16;
  float acc[8][8] = {};
  float denp = 0.f;
  for (int n0 = 0; n0 < 128; n0 += 32) {
    __syncthreads();
    const float* Lp = L + (size_t)(nbase + n0 + lr) * NK + lc;
    const float* Rp = R + (size_t)(nbase + n0 + lr) * NK + lc;
    float sq = 0.f;
#pragma unroll
    for (int j = 0; j < 4; ++j) {
      float4 v = *(const float4*)(Lp + j * 4);
      *(float4*)&Ls[lr][lc + j * 4] = v;
      sq += v.x * v.x + v.y * v.y + v.z * v.z + v.w * v.w;
      *(float4*)&Rs[lr][lc + j * 4] = *(const float4*)(Rp + j * 4);
    }
    if (z) denp += dflat[b * NN + nbase + n0 + lr] * sq;
    __syncthreads();
#pragma unroll
    for (int nn = 0; nn < 32; ++nn) {
      float a[8], bb[8];
      *(float4*)&a[0] = *(const float4*)&Ls[nn][k0];
      *(float4*)&a[4] = *(const float4*)&Ls[nn][k0 + 4];
      *(float4*)&bb[0] = *(const float4*)&Rs[nn][c0];
      *(float4*)&bb[4] = *(const float4*)&Rs[nn][c0 + 4];
#pragma unroll
      for (int i = 0; i < 8; ++i)
#pragma unroll
        for (int j = 0; j < 8; ++j)
          acc[i][j] = fmaf(a[i], bb[j], acc[i][j]);
    }
  }
#pragma unroll
  for (int i = 0; i < 8; ++i) {
    *(float4*)&O[(size_t)(k0 + i) * NK + c0] = *(float4*)&acc[i][0];
    *(float4*)&O[(size_t)(k0 + i) * NK + c0 + 4] = *(float4*)&acc[i][4];
  }
  if (z) {
    float tot = block_reduce_sum(denp, red);
    if (tid == 0) atomicAdd(&denb[b], tot);
  }
}

// -------- sum the NCH partials into adjraw / ssb --------
__global__ __launch_bounds__(256) void k_reduce(const float* __restrict__ padj,
                                                const float* __restrict__ pss,
                                                float* __restrict__ adjraw,
                                                float* __restrict__ ssb) {
  size_t i = (size_t)blockIdx.x * 256 + threadIdx.x;  // float4 index
  size_t stride4 = (size_t)NB * NK * NK / 4;
  const float4* pa = (const float4*)padj + i;
  const float4* ps = (const float4*)pss + i;
  float4 a = make_float4(0.f, 0.f, 0.f, 0.f);
  float4 s = make_float4(0.f, 0.f, 0.f, 0.f);
#pragma unroll
  for (int ch = 0; ch < NCH; ++ch) {
    float4 va = pa[(size_t)ch * stride4];
    float4 vs = ps[(size_t)ch * stride4];
    a.x += va.x; a.y += va.y; a.z += va.z; a.w += va.w;
    s.x += vs.x; s.y += vs.y; s.z += vs.z; s.w += vs.w;
  }
  ((float4*)adjraw)[i] = a;
  ((float4*)ssb)[i] = s;
}

// -------- per-batch epilogue: losses + degree-normalized out_adj --------
__global__ __launch_bounds__(256) void k_finalize(const float* __restrict__ denb,
                                                  const float* __restrict__ adjraw,
                                                  const float* __restrict__ ssb,
                                                  float* __restrict__ out_adj,
                                                  float* __restrict__ out_loss) {
  __shared__ float red[256];
  __shared__ float sd[NK];
  int b = blockIdx.x, tid = threadIdx.x;
  const float* AR = adjraw + (size_t)b * NK * NK;
  const float* SS = ssb + (size_t)b * NK * NK;

  // mincut numerator = trace(sm^T A sm)
  float tv = (tid < NK) ? AR[tid * NK + tid] : 0.f;
  float trace = block_reduce_sum(tv, red);

  float den = denb[b];

  // ||ss||_F
  float n2 = 0.f;
  for (int i4 = tid; i4 < NK * NK / 4; i4 += 256) {
    float4 v = *(const float4*)(SS + (size_t)i4 * 4);
    n2 += v.x * v.x + v.y * v.y + v.z * v.z + v.w * v.w;
  }
  float nrm = sqrtf(block_reduce_sum(n2, red));

  // ortho = || ss/||ss|| - I/sqrt(K) ||_F
  const float isk = 0.08838834764831845f;  // 1/sqrt(128)
  float osum = 0.f;
  for (int i = tid; i < NK * NK; i += 256) {
    int r = i >> 7, c = i & (NK - 1);
    float val = SS[i] / nrm - ((r == c) ? isk : 0.f);
    osum += val * val;
  }
  float ortho = sqrtf(block_reduce_sum(osum, red));

  // zero-diag row sums -> d
  if (tid < NK) {
    float rsumv = 0.f;
    const float* row = AR + (size_t)tid * NK;
    for (int j = 0; j < NK; ++j) rsumv += (j == tid) ? 0.f : row[j];
    sd[tid] = sqrtf(rsumv) + EPSV;
  }
  __syncthreads();

  float* OA = out_adj + (size_t)b * NK * NK;
  for (int i = tid; i < NK * NK; i += 256) {
    int r = i >> 7, c = i & (NK - 1);
    OA[i] = (r == c) ? 0.f : AR[i] / (sd[r] * sd[c]);
  }

  if (tid == 0) {
    atomicAdd(&out_loss[0], -(trace / den) * (1.0f / NB));
    atomicAdd(&out_loss[1], ortho * (1.0f / NB));
  }
}

extern "C" void kernel_launch(void* const* d_in, const int* in_sizes, int n_in,
                              void* d_out, int out_size, void* d_ws, size_t ws_size,
                              hipStream_t stream) {
  const float* x = (const float*)d_in[0];
  const float* s = (const float*)d_in[1];
  const float* adj = (const float*)d_in[2];
  const int* fidx = (const int*)d_in[3];
  int T = in_sizes[3];

  // output layout: sm | out | out_adj | mincut_loss | ortho_loss
  float* out_sm = (float*)d_out;
  float* out_feat = out_sm + (size_t)NB * NN * NK;
  float* out_adj = out_feat + (size_t)NB * NK * NF;
  float* out_loss = out_adj + (size_t)NB * NK * NK;

  // workspace layout
  float* Y = (float*)d_ws;                           // B*N*K
  float* dflat = Y + (size_t)NB * NN * NK;           // B*N
  float* padj = dflat + (size_t)NB * NN;             // NCH*B*K*K
  float* pss = padj + (size_t)NCH * NB * NK * NK;    // NCH*B*K*K
  float* adjraw = pss + (size_t)NCH * NB * NK * NK;  // B*K*K
  float* ssb = adjraw + (size_t)NB * NK * NK;        // B*K*K
  float* denb = ssb + (size_t)NB * NK * NK;          // B
  int* rowof = (int*)(denb + NB);                    // B*N ints

  hipMemsetAsync(out_sm, 0, (size_t)NB * NN * NK * sizeof(float), stream);
  hipMemsetAsync(out_loss, 0, 2 * sizeof(float), stream);
  hipMemsetAsync(denb, 0, NB * sizeof(float), stream);
  hipMemsetAsync(rowof, 0xFF, (size_t)NB * NN * sizeof(int), stream);

  k_build_rowof<<<(T + 255) / 256, 256, 0, stream>>>(fidx, rowof, T);
  k_softmax<<<(T + 3) / 4, 256, 0, stream>>>(s, fidx, out_sm, T);
  k_adj_sm<<<dim3(NN / 64, NB), 256, 0, stream>>>(adj, out_sm, Y, dflat);
  k_feat<<<dim3(NF / 32, NB), 256, 0, stream>>>(out_sm, x, rowof, out_feat);
  k_tt<<<dim3(NCH, NB, 2), 256, 0, stream>>>(out_sm, Y, dflat, padj, pss, denb);
  k_reduce<<<NB * NK * NK / 4 / 256, 256, 0, stream>>>(padj, pss, adjraw, ssb);
  k_finalize<<<NB, 256, 0, stream>>>(denb, adjraw, ssb, out_adj, out_loss);
}

// Round 3
// 285.244 us; speedup vs baseline: 1.5859x; 1.1338x over previous
//
#include <hip/hip_runtime.h>

constexpr int NB = 16, NN = 1024, NF = 512, NK = 128;
constexpr int NCH = 8;     // k_tt row chunks (128 rows each)
constexpr int MSPLIT = 2;  // k_adj_sm reduction split
constexpr float EPSV = 1e-15f;

// -------- build inverse row map: row_of[flat_index[t]] = t --------
__global__ __launch_bounds__(256) void k_build_rowof(const int* __restrict__ fidx,
                                                     int* __restrict__ rowof, int T) {
  int t = blockIdx.x * 256 + threadIdx.x;
  if (t < T) rowof[fidx[t]] = t;
}

// -------- dense softmax: every (b,n) row; invalid rows -> zeros --------
__global__ __launch_bounds__(256) void k_softmax(const float* __restrict__ s,
                                                 const int* __restrict__ rowof,
                                                 float* __restrict__ sm) {
  int d = blockIdx.x * 4 + (threadIdx.x >> 6);
  int lane = threadIdx.x & 63;
  float* orow = sm + (size_t)d * NK;
  int ri = rowof[d];
  if (ri < 0) {
    orow[lane] = 0.f;
    orow[lane + 64] = 0.f;
    return;
  }
  const float* row = s + (size_t)ri * NK;
  float a = row[lane], b2 = row[lane + 64];
  float m = fmaxf(a, b2);
#pragma unroll
  for (int off = 32; off; off >>= 1) m = fmaxf(m, __shfl_xor(m, off, 64));
  float e0 = expf(a - m), e1 = expf(b2 - m);
  float ssum = e0 + e1;
#pragma unroll
  for (int off = 32; off; off >>= 1) ssum += __shfl_xor(ssum, off, 64);
  float inv = 1.0f / ssum;
  orow[lane] = e0 * inv;
  orow[lane + 64] = e1 * inv;
}

// -------- Yp[z][b] = adj[b][:, mz] @ sm[b][mz, :]; fused dflat partials --------
// grid (N/64, B, MSPLIT), 256 threads, 64x128 tile, micro 4x8
__global__ __launch_bounds__(256) void k_adj_sm(const float* __restrict__ adj,
                                                const float* __restrict__ sm,
                                                float* __restrict__ Yp,
                                                float* __restrict__ dfp) {
  __shared__ float At[64][68];   // natural [n_local][m_local]
  __shared__ float Ss[64][128];  // [m_local][k]
  int b = blockIdx.y;
  int n0 = blockIdx.x * 64;
  int z = blockIdx.z;
  const float* A = adj + (size_t)b * NN * NN;
  const float* S = sm + (size_t)b * NN * NK;
  int tid = threadIdx.x;
  int tr = tid >> 4, tc = tid & 15;
  int r0 = tr * 4, c0 = tc * 8;
  float acc[4][8] = {};
  float rsum[4] = {0.f, 0.f, 0.f, 0.f};
  for (int m0 = z * (NN / MSPLIT); m0 < (z + 1) * (NN / MSPLIT); m0 += 64) {
    __syncthreads();
    // A tile 64x64 natural layout (float4 stores, conflict-free); fused row-sum
#pragma unroll
    for (int p = 0; p < 4; ++p) {
      int r = p * 16 + tr;
      float4 v = *(const float4*)(A + (size_t)(n0 + r) * NN + m0 + tc * 4);
      *(float4*)&At[r][tc * 4] = v;
      float ps = v.x + v.y + v.z + v.w;
      ps += __shfl_xor(ps, 1, 64); ps += __shfl_xor(ps, 2, 64);
      ps += __shfl_xor(ps, 4, 64); ps += __shfl_xor(ps, 8, 64);
      rsum[p] += ps;
    }
    // sm tile 64x128
#pragma unroll
    for (int p = 0; p < 8; ++p) {
      int r = p * 8 + (tid >> 5);
      int c = (tid & 31) * 4;
      *(float4*)&Ss[r][c] = *(const float4*)(S + (size_t)(m0 + r) * NK + c);
    }
    __syncthreads();
#pragma unroll
    for (int mm = 0; mm < 64; ++mm) {
      // broadcast scalar reads (16 lanes/addr), 2-way max -> free
      float a0 = At[r0 + 0][mm], a1 = At[r0 + 1][mm];
      float a2 = At[r0 + 2][mm], a3 = At[r0 + 3][mm];
      float bb[8];
      *(float4*)&bb[0] = *(const float4*)&Ss[mm][c0];
      *(float4*)&bb[4] = *(const float4*)&Ss[mm][c0 + 4];
#pragma unroll
      for (int j = 0; j < 8; ++j) {
        acc[0][j] = fmaf(a0, bb[j], acc[0][j]);
        acc[1][j] = fmaf(a1, bb[j], acc[1][j]);
        acc[2][j] = fmaf(a2, bb[j], acc[2][j]);
        acc[3][j] = fmaf(a3, bb[j], acc[3][j]);
      }
    }
  }
  float* Yb = Yp + ((size_t)z * NB + b) * NN * NK;
#pragma unroll
  for (int i = 0; i < 4; ++i) {
    *(float4*)(Yb + (size_t)(n0 + r0 + i) * NK + c0) = *(float4*)&acc[i][0];
    *(float4*)(Yb + (size_t)(n0 + r0 + i) * NK + c0 + 4) = *(float4*)&acc[i][4];
  }
  if (tc == 0) {
#pragma unroll
    for (int p = 0; p < 4; ++p)
      dfp[((size_t)z * NB + b) * NN + n0 + p * 16 + tr] = rsum[p];
  }
}

// -------- dflat = dfp[0] + dfp[1] --------
__global__ __launch_bounds__(256) void k_dflat(const float* __restrict__ dfp,
                                               float* __restrict__ dflat) {
  int i = blockIdx.x * 256 + threadIdx.x;
  dflat[i] = dfp[i] + dfp[NB * NN + i];
}

// -------- out[b] = sm[b]^T @ x_gathered[b]  (K x F), n-split 2 --------
// grid (F/64, B, 2), 512 threads, 128x64 tile, micro 4x4
__global__ __launch_bounds__(512) void k_feat(const float* __restrict__ sm,
                                              const float* __restrict__ x,
                                              const int* __restrict__ rowof,
                                              float* __restrict__ out0,
                                              float* __restrict__ out1) {
  __shared__ float Ss[64][128];
  __shared__ float Xs[64][68];
  int b = blockIdx.y;
  int fbase = blockIdx.x * 64;
  int z = blockIdx.z;
  const float* S = sm + (size_t)b * NN * NK;
  int tid = threadIdx.x;
  int tk = tid >> 4, tf = tid & 15;  // k0 = 4*tk (0..124), f0 = 4*tf (0..60)
  int k0 = tk * 4, f0 = tf * 4;
  float acc[4][4] = {};
  for (int n0 = z * (NN / 2); n0 < (z + 1) * (NN / 2); n0 += 64) {
    __syncthreads();
#pragma unroll
    for (int p = 0; p < 4; ++p) {
      int r = p * 16 + (tid >> 5);
      int c = (tid & 31) * 4;
      *(float4*)&Ss[r][c] = *(const float4*)(S + (size_t)(n0 + r) * NK + c);
    }
#pragma unroll
    for (int p = 0; p < 2; ++p) {
      int r = p * 32 + (tid >> 4);
      int c = (tid & 15) * 4;
      int ri = rowof[b * NN + n0 + r];
      float4 v = make_float4(0.f, 0.f, 0.f, 0.f);
      if (ri >= 0) v = *(const float4*)(x + (size_t)ri * NF + fbase + c);
      *(float4*)&Xs[r][c] = v;
    }
    __syncthreads();
#pragma unroll
    for (int nn = 0; nn < 64; ++nn) {
      float a[4], bb[4];
      *(float4*)a = *(const float4*)&Ss[nn][k0];
      *(float4*)bb = *(const float4*)&Xs[nn][f0];
#pragma unroll
      for (int i = 0; i < 4; ++i)
#pragma unroll
        for (int j = 0; j < 4; ++j)
          acc[i][j] = fmaf(a[i], bb[j], acc[i][j]);
    }
  }
  float* O = (z ? out1 : out0) + (size_t)b * NK * NF;
#pragma unroll
  for (int i = 0; i < 4; ++i)
    *(float4*)(O + (size_t)(k0 + i) * NF + fbase + f0) = *(float4*)&acc[i][0];
}

// -------- out_feat += partial1 --------
__global__ __launch_bounds__(256) void k_red_feat(float* __restrict__ out0,
                                                  const float* __restrict__ out1) {
  size_t i = (size_t)blockIdx.x * 256 + threadIdx.x;
  float4 a = ((const float4*)out0)[i];
  float4 c = ((const float4*)out1)[i];
  a.x += c.x; a.y += c.y; a.z += c.z; a.w += c.w;
  ((float4*)out0)[i] = a;
}

// -------- partials: padj[ch][b] = sm_ch^T Y_ch, pss[ch][b] = sm_ch^T sm_ch --------
// grid (NCH, B, 2), 512 threads, micro 8x4; fused mincut-den partial (z=1)
__global__ __launch_bounds__(512) void k_tt(const float* __restrict__ sm,
                                            const float* __restrict__ Yp,
                                            const float* __restrict__ dflat,
                                            float* __restrict__ padj,
                                            float* __restrict__ pss,
                                            float* __restrict__ denb) {
  __shared__ float Ls[32][128];
  __shared__ float Rs[32][128];
  __shared__ float red[512];
  int ch = blockIdx.x, b = blockIdx.y, z = blockIdx.z;
  int nbase = ch * 128;
  const float* L = sm + (size_t)b * NN * NK;
  const float* R0 = Yp + (size_t)b * NN * NK;
  const float* R1 = Yp + ((size_t)NB + b) * NN * NK;
  float* O = (z ? pss : padj) + ((size_t)ch * NB + b) * NK * NK;
  int tid = threadIdx.x;
  int tkk = tid >> 5, tcc = tid & 31;  // k0 = 8*tkk, c0 = 4*tcc
  int k0 = tkk * 8, c0 = tcc * 4;
  int lr = tid >> 4, c4 = tid & 15;  // loader: row lr, float4 col c4 / c4+16
  float acc[8][4] = {};
  float denp = 0.f;
  float (&RR)[32][128] = z ? Ls : Rs;
  for (int n0 = 0; n0 < 128; n0 += 32) {
    __syncthreads();
    int grow = nbase + n0 + lr;
    const float* Lp = L + (size_t)grow * NK;
    float df = z ? dflat[b * NN + grow] : 0.f;
#pragma unroll
    for (int j = 0; j < 2; ++j) {
      int cc = (c4 + 16 * j) * 4;
      float4 v = *(const float4*)(Lp + cc);
      *(float4*)&Ls[lr][cc] = v;
      if (z) {
        denp += df * (v.x * v.x + v.y * v.y + v.z * v.z + v.w * v.w);
      } else {
        float4 r0v = *(const float4*)(R0 + (size_t)grow * NK + cc);
        float4 r1v = *(const float4*)(R1 + (size_t)grow * NK + cc);
        r0v.x += r1v.x; r0v.y += r1v.y; r0v.z += r1v.z; r0v.w += r1v.w;
        *(float4*)&Rs[lr][cc] = r0v;
      }
    }
    __syncthreads();
#pragma unroll
    for (int nn = 0; nn < 32; ++nn) {
      float a[8], bb[4];
      *(float4*)&a[0] = *(const float4*)&Ls[nn][k0];
      *(float4*)&a[4] = *(const float4*)&Ls[nn][k0 + 4];
      *(float4*)bb = *(const float4*)&RR[nn][c0];
#pragma unroll
      for (int i = 0; i < 8; ++i)
#pragma unroll
        for (int j = 0; j < 4; ++j)
          acc[i][j] = fmaf(a[i], bb[j], acc[i][j]);
    }
  }
#pragma unroll
  for (int i = 0; i < 8; ++i)
    *(float4*)&O[(size_t)(k0 + i) * NK + c0] = *(float4*)&acc[i][0];
  if (z) {
    red[tid] = denp;
    __syncthreads();
#pragma unroll
    for (int sft = 256; sft; sft >>= 1) {
      if (tid < sft) red[tid] += red[tid + sft];
      __syncthreads();
    }
    if (tid == 0) atomicAdd(&denb[b], red[0]);
  }
}

// -------- sum the NCH partials into adjraw(->out_adj region) / ssb --------
__global__ __launch_bounds__(256) void k_reduce(const float* __restrict__ padj,
                                                const float* __restrict__ pss,
                                                float* __restrict__ adjraw,
                                                float* __restrict__ ssb) {
  size_t i = (size_t)blockIdx.x * 256 + threadIdx.x;  // float4 index
  size_t stride4 = (size_t)NB * NK * NK / 4;
  const float4* pa = (const float4*)padj + i;
  const float4* ps = (const float4*)pss + i;
  float4 a = make_float4(0.f, 0.f, 0.f, 0.f);
  float4 s = make_float4(0.f, 0.f, 0.f, 0.f);
#pragma unroll
  for (int ch = 0; ch < NCH; ++ch) {
    float4 va = pa[(size_t)ch * stride4];
    float4 vs = ps[(size_t)ch * stride4];
    a.x += va.x; a.y += va.y; a.z += va.z; a.w += va.w;
    s.x += vs.x; s.y += vs.y; s.z += vs.z; s.w += vs.w;
  }
  ((float4*)adjraw)[i] = a;
  ((float4*)ssb)[i] = s;
}

__device__ __forceinline__ float block_reduce_sum(float v, float* red) {
  int tid = threadIdx.x;
  red[tid] = v;
  __syncthreads();
#pragma unroll
  for (int sft = 128; sft; sft >>= 1) {
    if (tid < sft) red[tid] += red[tid + sft];
    __syncthreads();
  }
  float r = red[0];
  __syncthreads();
  return r;
}

// -------- per-batch epilogue (in-place on out_adj holding adjraw) --------
__global__ __launch_bounds__(256) void k_finalize(const float* __restrict__ denb,
                                                  const float* __restrict__ ssb,
                                                  float* __restrict__ out_adj,
                                                  float* __restrict__ out_loss) {
  __shared__ float red[256];
  __shared__ float sd[NK];
  int b = blockIdx.x, tid = threadIdx.x;
  float* AR = out_adj + (size_t)b * NK * NK;
  const float* SS = ssb + (size_t)b * NK * NK;

  float tv = (tid < NK) ? AR[tid * NK + tid] : 0.f;
  float trace = block_reduce_sum(tv, red);
  float den = denb[b];

  float n2 = 0.f;
  for (int i4 = tid; i4 < NK * NK / 4; i4 += 256) {
    float4 v = *(const float4*)(SS + (size_t)i4 * 4);
    n2 += v.x * v.x + v.y * v.y + v.z * v.z + v.w * v.w;
  }
  float nrm = sqrtf(block_reduce_sum(n2, red));

  const float isk = 0.08838834764831845f;  // 1/sqrt(128)
  float osum = 0.f;
  for (int i = tid; i < NK * NK; i += 256) {
    int r = i >> 7, c = i & (NK - 1);
    float val = SS[i] / nrm - ((r == c) ? isk : 0.f);
    osum += val * val;
  }
  float ortho = sqrtf(block_reduce_sum(osum, red));

  if (tid < NK) {
    float rsumv = 0.f;
    const float* row = AR + (size_t)tid * NK;
    for (int j = 0; j < NK; ++j) rsumv += (j == tid) ? 0.f : row[j];
    sd[tid] = sqrtf(rsumv) + EPSV;
  }
  __syncthreads();

  for (int i = tid; i < NK * NK; i += 256) {
    int r = i >> 7, c = i & (NK - 1);
    AR[i] = (r == c) ? 0.f : AR[i] / (sd[r] * sd[c]);
  }

  if (tid == 0) {
    atomicAdd(&out_loss[0], -(trace / den) * (1.0f / NB));
    atomicAdd(&out_loss[1], ortho * (1.0f / NB));
  }
}

extern "C" void kernel_launch(void* const* d_in, const int* in_sizes, int n_in,
                              void* d_out, int out_size, void* d_ws, size_t ws_size,
                              hipStream_t stream) {
  const float* x = (const float*)d_in[0];
  const float* s = (const float*)d_in[1];
  const float* adj = (const float*)d_in[2];
  const int* fidx = (const int*)d_in[3];
  int T = in_sizes[3];

  // output layout: sm | out | out_adj | mincut_loss | ortho_loss
  float* out_sm = (float*)d_out;
  float* out_feat = out_sm + (size_t)NB * NN * NK;
  float* out_adj = out_feat + (size_t)NB * NK * NF;
  float* out_loss = out_adj + (size_t)NB * NK * NK;

  // workspace layout (~39 MB)
  float* Yp = (float*)d_ws;                          // MSPLIT*B*N*K
  float* dfp = Yp + (size_t)MSPLIT * NB * NN * NK;   // MSPLIT*B*N
  float* dflat = dfp + (size_t)MSPLIT * NB * NN;     // B*N
  float* padj = dflat + (size_t)NB * NN;             // NCH*B*K*K
  float* pss = padj + (size_t)NCH * NB * NK * NK;    // NCH*B*K*K
  float* ssb = pss + (size_t)NCH * NB * NK * NK;     // B*K*K
  float* outf1 = ssb + (size_t)NB * NK * NK;         // B*K*F
  float* denb = outf1 + (size_t)NB * NK * NF;        // B
  int* rowof = (int*)(denb + NB);                    // B*N ints

  hipMemsetAsync(out_loss, 0, 2 * sizeof(float), stream);
  hipMemsetAsync(denb, 0, NB * sizeof(float), stream);
  hipMemsetAsync(rowof, 0xFF, (size_t)NB * NN * sizeof(int), stream);

  k_build_rowof<<<(T + 255) / 256, 256, 0, stream>>>(fidx, rowof, T);
  k_softmax<<<NB * NN / 4, 256, 0, stream>>>(s, rowof, out_sm);
  k_adj_sm<<<dim3(NN / 64, NB, MSPLIT), 256, 0, stream>>>(adj, out_sm, Yp, dfp);
  k_dflat<<<NB * NN / 256, 256, 0, stream>>>(dfp, dflat);
  k_feat<<<dim3(NF / 64, NB, 2), 512, 0, stream>>>(out_sm, x, rowof, out_feat, outf1);
  k_red_feat<<<NB * NK * NF / 4 / 256, 256, 0, stream>>>(out_feat, outf1);
  k_tt<<<dim3(NCH, NB, 2), 512, 0, stream>>>(out_sm, Yp, dflat, padj, pss, denb);
  k_reduce<<<NB * NK * NK / 4 / 256, 256, 0, stream>>>(padj, pss, out_adj, ssb);
  k_finalize<<<NB, 256, 0, stream>>>(denb, ssb, out_adj, out_loss);
}

// Round 5
// 279.562 us; speedup vs baseline: 1.6181x; 1.0203x over previous
//
#include <hip/hip_runtime.h>

constexpr int NB = 16, NN = 1024, NF = 512, NK = 128;
constexpr int NCH = 8;     // k_tt n-chunks (128 rows each)
constexpr int MSPLIT = 2;  // k_adj_sm reduction split
constexpr float EPSV = 1e-15f;

typedef __attribute__((ext_vector_type(8))) short bf16x8;
typedef __attribute__((ext_vector_type(4))) float f32x4;

__device__ __forceinline__ f32x4 MFMA(bf16x8 a, bf16x8 b, f32x4 c) {
  return __builtin_amdgcn_mfma_f32_16x16x32_bf16(a, b, c, 0, 0, 0);
}

__device__ __forceinline__ unsigned short bf16_rn(float f) {
  unsigned int u = __float_as_uint(f);
  u += 0x7fffu + ((u >> 16) & 1u);
  return (unsigned short)(u >> 16);
}
__device__ __forceinline__ float bf16f(unsigned short h) {
  return __uint_as_float((unsigned int)h << 16);
}
__device__ __forceinline__ void split2(float f, unsigned short& h, unsigned short& lo) {
  h = bf16_rn(f);
  lo = bf16_rn(f - bf16f(h));
}

// -------- build inverse row map: row_of[flat_index[t]] = t --------
__global__ __launch_bounds__(256) void k_build_rowof(const int* __restrict__ fidx,
                                                     int* __restrict__ rowof, int T) {
  int t = blockIdx.x * 256 + threadIdx.x;
  if (t < T) rowof[fidx[t]] = t;
}

// -------- softmax (dense; invalid rows -> 0) + emit fp32 sm and bf16 hi/lo smT --------
// grid (B*N/64), 256 threads; block = 64 rows of one b
__global__ __launch_bounds__(256) void k_softmax(const float* __restrict__ s,
                                                 const int* __restrict__ rowof,
                                                 float* __restrict__ sm,
                                                 unsigned short* __restrict__ smTh,
                                                 unsigned short* __restrict__ smTl) {
  __shared__ float P[64][129];  // pad 129: phase-1/2b bank-friendly
  int blk = blockIdx.x;
  int b = blk >> 4, n0 = (blk & 15) * 64;
  int tid = threadIdx.x, wv = tid >> 6, lane = tid & 63;
  // phase 1: each wave does 16 rows
  for (int i = 0; i < 16; ++i) {
    int r = wv * 16 + i;
    int ri = rowof[b * NN + n0 + r];
    float e0 = 0.f, e1 = 0.f;
    if (ri >= 0) {
      const float* row = s + (size_t)ri * NK;
      float a = row[lane], c = row[lane + 64];
      float m = fmaxf(a, c);
#pragma unroll
      for (int off = 32; off; off >>= 1) m = fmaxf(m, __shfl_xor(m, off, 64));
      e0 = expf(a - m);
      e1 = expf(c - m);
      float sum = e0 + e1;
#pragma unroll
      for (int off = 32; off; off >>= 1) sum += __shfl_xor(sum, off, 64);
      float inv = 1.0f / sum;
      e0 *= inv;
      e1 *= inv;
    }
    P[r][lane] = e0;
    P[r][lane + 64] = e1;
  }
  __syncthreads();
  // phase 2a: fp32 sm, coalesced float4 stores
  int r2 = tid >> 2, cb = (tid & 3) * 32;
  float* orow = sm + ((size_t)b * NN + n0 + r2) * NK + cb;
#pragma unroll
  for (int j = 0; j < 8; ++j) {
    float4 v = make_float4(P[r2][cb + j * 4], P[r2][cb + j * 4 + 1],
                           P[r2][cb + j * 4 + 2], P[r2][cb + j * 4 + 3]);
    *(float4*)(orow + j * 4) = v;
  }
  // phase 2b: transposed bf16 hi/lo; wave w covers k in [w*32, w*32+32)
  for (int j = 0; j < 32; ++j) {
    int k = wv * 32 + j;
    float v = P[lane][k];
    unsigned short h, lo;
    split2(v, h, lo);
    size_t off = ((size_t)b * NK + k) * NN + n0 + lane;
    smTh[off] = h;
    smTl[off] = lo;
  }
}

// -------- Yt[k][n] = sum_m sm[m][k]*adj[m][n]  (adj symmetric => = Y[n][k]) --------
// grid (N/64, B, MSPLIT), 256 thr / 4 waves; wave w: k-rows [w*32,w*32+32), n 64 cols
__global__ __launch_bounds__(256) void k_adj_sm(const float* __restrict__ adj,
                                                const unsigned short* __restrict__ smTh,
                                                const unsigned short* __restrict__ smTl,
                                                float* __restrict__ Ytp,
                                                float* __restrict__ dfp) {
  __shared__ __align__(16) unsigned short STh[128][72], STl[128][72];  // [k][m_loc]
  __shared__ __align__(16) unsigned short ADh[64][72], ADl[64][72];    // [n_loc][m_loc]
  int b = blockIdx.y, n0 = blockIdx.x * 64, z = blockIdx.z;
  int tid = threadIdx.x, wv = tid >> 6, l = tid & 63;
  int lr = l & 15, lk = l >> 4;
  int tk = tid >> 1, th = tid & 1;  // smT stager: row tk, 32-col half th
  int sn = tid >> 2, sq = tid & 3;  // adj stager
  const float* A = adj + (size_t)b * NN * NN;
  f32x4 zero = {0.f, 0.f, 0.f, 0.f};
  f32x4 acc[2][4];
#pragma unroll
  for (int i = 0; i < 2; ++i)
#pragma unroll
    for (int j = 0; j < 4; ++j) acc[i][j] = zero;
  float rsacc = 0.f;
  for (int m0 = z * (NN / MSPLIT); m0 < (z + 1) * (NN / MSPLIT); m0 += 64) {
    __syncthreads();
    {  // stage smT chunk [128][64] hi/lo: 32 shorts per thread per buffer
      const uint4* gh = (const uint4*)(smTh + ((size_t)b * NK + tk) * NN + m0 + th * 32);
      const uint4* gl = (const uint4*)(smTl + ((size_t)b * NK + tk) * NN + m0 + th * 32);
#pragma unroll
      for (int j = 0; j < 4; ++j) {
        *(uint4*)&STh[tk][th * 32 + j * 8] = gh[j];
        *(uint4*)&STl[tk][th * 32 + j * 8] = gl[j];
      }
    }
    {  // stage adj tile [64][64] fp32 -> bf16 hi/lo; fused row-sum
      const float* ap = A + (size_t)(n0 + sn) * NN + m0 + sq * 16;
      float ps = 0.f;
#pragma unroll
      for (int j = 0; j < 4; ++j) {
        float4 v = *(const float4*)(ap + j * 4);
        ushort4 vh, vl;
        split2(v.x, vh.x, vl.x);
        split2(v.y, vh.y, vl.y);
        split2(v.z, vh.z, vl.z);
        split2(v.w, vh.w, vl.w);
        *(ushort4*)&ADh[sn][sq * 16 + j * 4] = vh;
        *(ushort4*)&ADl[sn][sq * 16 + j * 4] = vl;
        ps += v.x + v.y + v.z + v.w;
      }
      ps += __shfl_xor(ps, 1, 64);
      ps += __shfl_xor(ps, 2, 64);
      rsacc += ps;
    }
    __syncthreads();
#pragma unroll
    for (int s = 0; s < 2; ++s) {
      bf16x8 ah0 = *(const bf16x8*)&STh[wv * 32 + lr][s * 32 + lk * 8];
      bf16x8 ah1 = *(const bf16x8*)&STh[wv * 32 + 16 + lr][s * 32 + lk * 8];
      bf16x8 al0 = *(const bf16x8*)&STl[wv * 32 + lr][s * 32 + lk * 8];
      bf16x8 al1 = *(const bf16x8*)&STl[wv * 32 + 16 + lr][s * 32 + lk * 8];
#pragma unroll
      for (int nt = 0; nt < 4; ++nt) {
        bf16x8 bh = *(const bf16x8*)&ADh[nt * 16 + lr][s * 32 + lk * 8];
        bf16x8 bl = *(const bf16x8*)&ADl[nt * 16 + lr][s * 32 + lk * 8];
        acc[0][nt] = MFMA(ah0, bh, acc[0][nt]);
        acc[0][nt] = MFMA(ah0, bl, acc[0][nt]);
        acc[0][nt] = MFMA(al0, bh, acc[0][nt]);
        acc[1][nt] = MFMA(ah1, bh, acc[1][nt]);
        acc[1][nt] = MFMA(ah1, bl, acc[1][nt]);
        acc[1][nt] = MFMA(al1, bh, acc[1][nt]);
      }
    }
  }
  // store Yt partial fp32: D row=(lk*4+reg) -> k, col=lr -> n
  float* Yb = Ytp + ((size_t)z * NB + b) * NK * NN;
#pragma unroll
  for (int kt = 0; kt < 2; ++kt)
#pragma unroll
    for (int nt = 0; nt < 4; ++nt)
#pragma unroll
      for (int reg = 0; reg < 4; ++reg) {
        int k = wv * 32 + kt * 16 + lk * 4 + reg;
        int n = n0 + nt * 16 + lr;
        Yb[(size_t)k * NN + n] = acc[kt][nt][reg];
      }
  if (sq == 0) dfp[((size_t)z * NB + b) * NN + n0 + sn] = rsacc;
}

// -------- dflat = dfp[0] + dfp[1] --------
__global__ __launch_bounds__(256) void k_dflat(const float* __restrict__ dfp,
                                               float* __restrict__ dflat) {
  int i = blockIdx.x * 256 + threadIdx.x;
  dflat[i] = dfp[i] + dfp[NB * NN + i];
}

// -------- out[b] = sm[b]^T @ x_gathered[b]  (K x F), n-split 2 (fp32 VALU) --------
__global__ __launch_bounds__(512) void k_feat(const float* __restrict__ sm,
                                              const float* __restrict__ x,
                                              const int* __restrict__ rowof,
                                              float* __restrict__ out0,
                                              float* __restrict__ out1) {
  __shared__ float Ss[64][128];
  __shared__ float Xs[64][68];
  int b = blockIdx.y;
  int fbase = blockIdx.x * 64;
  int z = blockIdx.z;
  const float* S = sm + (size_t)b * NN * NK;
  int tid = threadIdx.x;
  int tk = tid >> 4, tf = tid & 15;
  int k0 = tk * 4, f0 = tf * 4;
  float acc[4][4] = {};
  for (int n0 = z * (NN / 2); n0 < (z + 1) * (NN / 2); n0 += 64) {
    __syncthreads();
#pragma unroll
    for (int p = 0; p < 4; ++p) {
      int r = p * 16 + (tid >> 5);
      int c = (tid & 31) * 4;
      *(float4*)&Ss[r][c] = *(const float4*)(S + (size_t)(n0 + r) * NK + c);
    }
#pragma unroll
    for (int p = 0; p < 2; ++p) {
      int r = p * 32 + (tid >> 4);
      int c = (tid & 15) * 4;
      int ri = rowof[b * NN + n0 + r];
      float4 v = make_float4(0.f, 0.f, 0.f, 0.f);
      if (ri >= 0) v = *(const float4*)(x + (size_t)ri * NF + fbase + c);
      *(float4*)&Xs[r][c] = v;
    }
    __syncthreads();
#pragma unroll
    for (int nn = 0; nn < 64; ++nn) {
      float a[4], bb[4];
      *(float4*)a = *(const float4*)&Ss[nn][k0];
      *(float4*)bb = *(const float4*)&Xs[nn][f0];
#pragma unroll
      for (int i = 0; i < 4; ++i)
#pragma unroll
        for (int j = 0; j < 4; ++j)
          acc[i][j] = fmaf(a[i], bb[j], acc[i][j]);
    }
  }
  float* O = (z ? out1 : out0) + (size_t)b * NK * NF;
#pragma unroll
  for (int i = 0; i < 4; ++i)
    *(float4*)(O + (size_t)(k0 + i) * NF + fbase + f0) = *(float4*)&acc[i][0];
}

// -------- out_feat += partial1 --------
__global__ __launch_bounds__(256) void k_red_feat(float* __restrict__ out0,
                                                  const float* __restrict__ out1) {
  size_t i = (size_t)blockIdx.x * 256 + threadIdx.x;
  float4 a = ((const float4*)out0)[i];
  float4 c = ((const float4*)out1)[i];
  a.x += c.x; a.y += c.y; a.z += c.z; a.w += c.w;
  ((float4*)out0)[i] = a;
}

// -------- MFMA partials: padj[ch][b]=smT*Yt^T-chunk, pss[ch][b]=smT*sm-chunk --------
// grid (NCH, B, 2), 256 thr / 4 waves
__global__ __launch_bounds__(256) void k_tt(const unsigned short* __restrict__ smTh,
                                            const unsigned short* __restrict__ smTl,
                                            const float* __restrict__ Ytp,
                                            const float* __restrict__ dflat,
                                            float* __restrict__ padj,
                                            float* __restrict__ pss,
                                            float* __restrict__ denb) {
  __shared__ __align__(16) unsigned short STh[128][40], STl[128][40];  // [k][n_loc 32]
  __shared__ __align__(16) unsigned short YTh[128][40], YTl[128][40];
  __shared__ float red[256];
  int ch = blockIdx.x, b = blockIdx.y, z = blockIdx.z;
  int nbase = ch * 128;
  int tid = threadIdx.x, wv = tid >> 6, l = tid & 63;
  int lr = l & 15, lk = l >> 4;
  int tk = tid >> 1, th = tid & 1;
  f32x4 zero = {0.f, 0.f, 0.f, 0.f};
  f32x4 acc[2][8];
#pragma unroll
  for (int i = 0; i < 2; ++i)
#pragma unroll
    for (int j = 0; j < 8; ++j) acc[i][j] = zero;
  float denp = 0.f;
  for (int c = 0; c < 4; ++c) {
    int nn0 = nbase + c * 32;
    __syncthreads();
    {  // stage smT [128][32] hi/lo
      const unsigned short* gh = smTh + ((size_t)b * NK + tk) * NN + nn0 + th * 16;
      const unsigned short* gl = smTl + ((size_t)b * NK + tk) * NN + nn0 + th * 16;
#pragma unroll
      for (int j = 0; j < 4; ++j) {
        ushort4 hj = *(const ushort4*)(gh + j * 4);
        ushort4 lj = *(const ushort4*)(gl + j * 4);
        *(ushort4*)&STh[tk][th * 16 + j * 4] = hj;
        *(ushort4*)&STl[tk][th * 16 + j * 4] = lj;
        if (z) {  // fused mincut-den partial (each (k,n) elem once)
          float4 dv = *(const float4*)(dflat + (size_t)b * NN + nn0 + th * 16 + j * 4);
          float v0 = bf16f(hj.x) + bf16f(lj.x), v1 = bf16f(hj.y) + bf16f(lj.y);
          float v2 = bf16f(hj.z) + bf16f(lj.z), v3 = bf16f(hj.w) + bf16f(lj.w);
          denp += dv.x * v0 * v0 + dv.y * v1 * v1 + dv.z * v2 * v2 + dv.w * v3 * v3;
        }
      }
    }
    if (!z) {  // stage Yt = Ytp0+Ytp1, fp32 -> bf16 hi/lo
      const float* y0 = Ytp + ((size_t)b * NK + tk) * NN + nn0 + th * 16;
      const float* y1 = y0 + (size_t)NB * NK * NN;
#pragma unroll
      for (int j = 0; j < 4; ++j) {
        float4 a = *(const float4*)(y0 + j * 4);
        float4 cc = *(const float4*)(y1 + j * 4);
        a.x += cc.x; a.y += cc.y; a.z += cc.z; a.w += cc.w;
        ushort4 vh, vl;
        split2(a.x, vh.x, vl.x);
        split2(a.y, vh.y, vl.y);
        split2(a.z, vh.z, vl.z);
        split2(a.w, vh.w, vl.w);
        *(ushort4*)&YTh[tk][th * 16 + j * 4] = vh;
        *(ushort4*)&YTl[tk][th * 16 + j * 4] = vl;
      }
    }
    __syncthreads();
    unsigned short(*Bh)[40] = z ? STh : YTh;
    unsigned short(*Bl)[40] = z ? STl : YTl;
    bf16x8 ah0 = *(const bf16x8*)&STh[wv * 32 + lr][lk * 8];
    bf16x8 ah1 = *(const bf16x8*)&STh[wv * 32 + 16 + lr][lk * 8];
    bf16x8 al0 = *(const bf16x8*)&STl[wv * 32 + lr][lk * 8];
    bf16x8 al1 = *(const bf16x8*)&STl[wv * 32 + 16 + lr][lk * 8];
#pragma unroll
    for (int ct = 0; ct < 8; ++ct) {
      bf16x8 bh = *(const bf16x8*)&Bh[ct * 16 + lr][lk * 8];
      bf16x8 bl = *(const bf16x8*)&Bl[ct * 16 + lr][lk * 8];
      acc[0][ct] = MFMA(ah0, bh, acc[0][ct]);
      acc[0][ct] = MFMA(ah0, bl, acc[0][ct]);
      acc[0][ct] = MFMA(al0, bh, acc[0][ct]);
      acc[1][ct] = MFMA(ah1, bh, acc[1][ct]);
      acc[1][ct] = MFMA(ah1, bl, acc[1][ct]);
      acc[1][ct] = MFMA(al1, bh, acc[1][ct]);
    }
  }
  float* O = (z ? pss : padj) + ((size_t)ch * NB + b) * NK * NK;
#pragma unroll
  for (int kt = 0; kt < 2; ++kt)
#pragma unroll
    for (int ct = 0; ct < 8; ++ct)
#pragma unroll
      for (int reg = 0; reg < 4; ++reg)
        O[(size_t)(wv * 32 + kt * 16 + lk * 4 + reg) * NK + ct * 16 + lr] =
            acc[kt][ct][reg];
  if (z) {
    red[tid] = denp;
    __syncthreads();
#pragma unroll
    for (int sft = 128; sft; sft >>= 1) {
      if (tid < sft) red[tid] += red[tid + sft];
      __syncthreads();
    }
    if (tid == 0) atomicAdd(&denb[b], red[0]);
  }
}

// -------- sum the NCH partials into adjraw(->out_adj region) / ssb --------
__global__ __launch_bounds__(256) void k_reduce(const float* __restrict__ padj,
                                                const float* __restrict__ pss,
                                                float* __restrict__ adjraw,
                                                float* __restrict__ ssb) {
  size_t i = (size_t)blockIdx.x * 256 + threadIdx.x;
  size_t stride4 = (size_t)NB * NK * NK / 4;
  const float4* pa = (const float4*)padj + i;
  const float4* ps = (const float4*)pss + i;
  float4 a = make_float4(0.f, 0.f, 0.f, 0.f);
  float4 s = make_float4(0.f, 0.f, 0.f, 0.f);
#pragma unroll
  for (int ch = 0; ch < NCH; ++ch) {
    float4 va = pa[(size_t)ch * stride4];
    float4 vs = ps[(size_t)ch * stride4];
    a.x += va.x; a.y += va.y; a.z += va.z; a.w += va.w;
    s.x += vs.x; s.y += vs.y; s.z += vs.z; s.w += vs.w;
  }
  ((float4*)adjraw)[i] = a;
  ((float4*)ssb)[i] = s;
}

__device__ __forceinline__ float block_reduce_sum(float v, float* red) {
  int tid = threadIdx.x;
  red[tid] = v;
  __syncthreads();
#pragma unroll
  for (int sft = 128; sft; sft >>= 1) {
    if (tid < sft) red[tid] += red[tid + sft];
    __syncthreads();
  }
  float r = red[0];
  __syncthreads();
  return r;
}

// -------- per-batch epilogue (in-place on out_adj holding adjraw) --------
__global__ __launch_bounds__(256) void k_finalize(const float* __restrict__ denb,
                                                  const float* __restrict__ ssb,
                                                  float* __restrict__ out_adj,
                                                  float* __restrict__ out_loss) {
  __shared__ float red[256];
  __shared__ float sd[NK];
  int b = blockIdx.x, tid = threadIdx.x;
  float* AR = out_adj + (size_t)b * NK * NK;
  const float* SS = ssb + (size_t)b * NK * NK;

  float tv = (tid < NK) ? AR[tid * NK + tid] : 0.f;
  float trace = block_reduce_sum(tv, red);
  float den = denb[b];

  float n2 = 0.f;
  for (int i4 = tid; i4 < NK * NK / 4; i4 += 256) {
    float4 v = *(const float4*)(SS + (size_t)i4 * 4);
    n2 += v.x * v.x + v.y * v.y + v.z * v.z + v.w * v.w;
  }
  float nrm = sqrtf(block_reduce_sum(n2, red));

  const float isk = 0.08838834764831845f;  // 1/sqrt(128)
  float osum = 0.f;
  for (int i = tid; i < NK * NK; i += 256) {
    int r = i >> 7, c = i & (NK - 1);
    float val = SS[i] / nrm - ((r == c) ? isk : 0.f);
    osum += val * val;
  }
  float ortho = sqrtf(block_reduce_sum(osum, red));

  if (tid < NK) {
    float rsumv = 0.f;
    const float* row = AR + (size_t)tid * NK;
    for (int j = 0; j < NK; ++j) rsumv += (j == tid) ? 0.f : row[j];
    sd[tid] = sqrtf(rsumv) + EPSV;
  }
  __syncthreads();

  for (int i = tid; i < NK * NK; i += 256) {
    int r = i >> 7, c = i & (NK - 1);
    AR[i] = (r == c) ? 0.f : AR[i] / (sd[r] * sd[c]);
  }

  if (tid == 0) {
    atomicAdd(&out_loss[0], -(trace / den) * (1.0f / NB));
    atomicAdd(&out_loss[1], ortho * (1.0f / NB));
  }
}

extern "C" void kernel_launch(void* const* d_in, const int* in_sizes, int n_in,
                              void* d_out, int out_size, void* d_ws, size_t ws_size,
                              hipStream_t stream) {
  const float* x = (const float*)d_in[0];
  const float* s = (const float*)d_in[1];
  const float* adj = (const float*)d_in[2];
  const int* fidx = (const int*)d_in[3];
  int T = in_sizes[3];

  // output layout: sm | out | out_adj | mincut_loss | ortho_loss
  float* out_sm = (float*)d_out;
  float* out_feat = out_sm + (size_t)NB * NN * NK;
  float* out_adj = out_feat + (size_t)NB * NK * NF;
  float* out_loss = out_adj + (size_t)NB * NK * NK;

  // workspace (~46 MB)
  float* Ytp = (float*)d_ws;                           // 2*B*K*N fp32
  float* dfp = Ytp + (size_t)2 * NB * NK * NN;         // 2*B*N
  float* dflat = dfp + (size_t)2 * NB * NN;            // B*N
  float* padj = dflat + (size_t)NB * NN;               // NCH*B*K*K
  float* pss = padj + (size_t)NCH * NB * NK * NK;      // NCH*B*K*K
  float* ssb = pss + (size_t)NCH * NB * NK * NK;       // B*K*K
  float* outf1 = ssb + (size_t)NB * NK * NK;           // B*K*F
  float* denb = outf1 + (size_t)NB * NK * NF;          // B (16 floats)
  unsigned short* smTh = (unsigned short*)(denb + 16); // B*K*N bf16
  unsigned short* smTl = smTh + (size_t)NB * NK * NN;  // B*K*N bf16
  int* rowof = (int*)(smTl + (size_t)NB * NK * NN);    // B*N ints

  hipMemsetAsync(out_loss, 0, 2 * sizeof(float), stream);
  hipMemsetAsync(denb, 0, 16 * sizeof(float), stream);
  hipMemsetAsync(rowof, 0xFF, (size_t)NB * NN * sizeof(int), stream);

  k_build_rowof<<<(T + 255) / 256, 256, 0, stream>>>(fidx, rowof, T);
  k_softmax<<<NB * NN / 64, 256, 0, stream>>>(s, rowof, out_sm, smTh, smTl);
  k_adj_sm<<<dim3(NN / 64, NB, MSPLIT), 256, 0, stream>>>(adj, smTh, smTl, Ytp, dfp);
  k_dflat<<<NB * NN / 256, 256, 0, stream>>>(dfp, dflat);
  k_feat<<<dim3(NF / 64, NB, 2), 512, 0, stream>>>(out_sm, x, rowof, out_feat, outf1);
  k_red_feat<<<NB * NK * NF / 4 / 256, 256, 0, stream>>>(out_feat, outf1);
  k_tt<<<dim3(NCH, NB, 2), 256, 0, stream>>>(smTh, smTl, Ytp, dflat, padj, pss, denb);
  k_reduce<<<NB * NK * NK / 4 / 256, 256, 0, stream>>>(padj, pss, out_adj, ssb);
  k_finalize<<<NB, 256, 0, stream>>>(denb, ssb, out_adj, out_loss);
}

// Round 6
// 253.340 us; speedup vs baseline: 1.7856x; 1.1035x over previous
//
#include <hip/hip_runtime.h>

constexpr int NB = 16, NN = 1024, NF = 512, NK = 128;
constexpr int NCH = 8;     // k_tt n-chunks (128 rows each)
constexpr int MSPLIT = 2;  // k_adj_sm reduction split
constexpr float EPSV = 1e-15f;

typedef __attribute__((ext_vector_type(8))) short bf16x8;
typedef __attribute__((ext_vector_type(4))) float f32x4;

__device__ __forceinline__ f32x4 MFMA(bf16x8 a, bf16x8 b, f32x4 c) {
  return __builtin_amdgcn_mfma_f32_16x16x32_bf16(a, b, c, 0, 0, 0);
}

__device__ __forceinline__ unsigned short bf16_rn(float f) {
  unsigned int u = __float_as_uint(f);
  u += 0x7fffu + ((u >> 16) & 1u);
  return (unsigned short)(u >> 16);
}
__device__ __forceinline__ float bf16f(unsigned short h) {
  return __uint_as_float((unsigned int)h << 16);
}
__device__ __forceinline__ void split2(float f, unsigned short& h, unsigned short& lo) {
  h = bf16_rn(f);
  lo = bf16_rn(f - bf16f(h));
}

// -------- softmax (dense; invalid rows -> 0) + fp32 sm + bf16 hi/lo smT + rowof --------
// rowof via binary search on strictly-increasing flat_index (no scatter, no memset)
// grid (B*N/64), 256 threads; block = 64 rows of one b
__global__ __launch_bounds__(256) void k_softmax(const float* __restrict__ s,
                                                 const int* __restrict__ fidx, int T,
                                                 float* __restrict__ sm,
                                                 unsigned short* __restrict__ smTh,
                                                 unsigned short* __restrict__ smTl,
                                                 int* __restrict__ rowof) {
  __shared__ float P[64][129];
  __shared__ int rof[64];
  int blk = blockIdx.x;
  int b = blk >> 4, n0 = (blk & 15) * 64;
  int tid = threadIdx.x, wv = tid >> 6, lane = tid & 63;
  if (tid < 64) {
    int d = b * NN + n0 + tid;
    int lo = 0, hi = T;
    while (lo < hi) {
      int mid = (lo + hi) >> 1;
      if (fidx[mid] < d) lo = mid + 1; else hi = mid;
    }
    int r = (lo < T && fidx[lo] == d) ? lo : -1;
    rof[tid] = r;
    rowof[d] = r;
  }
  __syncthreads();
  // phase 1: each wave does 16 rows
  for (int i = 0; i < 16; ++i) {
    int r = wv * 16 + i;
    int ri = rof[r];
    float e0 = 0.f, e1 = 0.f;
    if (ri >= 0) {
      const float* row = s + (size_t)ri * NK;
      float a = row[lane], c = row[lane + 64];
      float m = fmaxf(a, c);
#pragma unroll
      for (int off = 32; off; off >>= 1) m = fmaxf(m, __shfl_xor(m, off, 64));
      e0 = expf(a - m);
      e1 = expf(c - m);
      float sum = e0 + e1;
#pragma unroll
      for (int off = 32; off; off >>= 1) sum += __shfl_xor(sum, off, 64);
      float inv = 1.0f / sum;
      e0 *= inv;
      e1 *= inv;
    }
    P[r][lane] = e0;
    P[r][lane + 64] = e1;
  }
  __syncthreads();
  // phase 2a: fp32 sm, coalesced float4 stores
  int r2 = tid >> 2, cb = (tid & 3) * 32;
  float* orow = sm + ((size_t)b * NN + n0 + r2) * NK + cb;
#pragma unroll
  for (int j = 0; j < 8; ++j) {
    float4 v = make_float4(P[r2][cb + j * 4], P[r2][cb + j * 4 + 1],
                           P[r2][cb + j * 4 + 2], P[r2][cb + j * 4 + 3]);
    *(float4*)(orow + j * 4) = v;
  }
  // phase 2b: transposed bf16 hi/lo; wave w covers k in [w*32, w*32+32)
  for (int j = 0; j < 32; ++j) {
    int k = wv * 32 + j;
    float v = P[lane][k];
    unsigned short h, lo;
    split2(v, h, lo);
    size_t off = ((size_t)b * NK + k) * NN + n0 + lane;
    smTh[off] = h;
    smTl[off] = lo;
  }
}

// -------- Yt[k][n] = sum_m sm[m][k]*adj[m][n]  (adj symmetric => = Y[n][k]) --------
// grid (N/64, B, MSPLIT), 256 thr / 4 waves
__global__ __launch_bounds__(256) void k_adj_sm(const float* __restrict__ adj,
                                                const unsigned short* __restrict__ smTh,
                                                const unsigned short* __restrict__ smTl,
                                                float* __restrict__ Ytp,
                                                float* __restrict__ dfp) {
  __shared__ __align__(16) unsigned short STh[128][72], STl[128][72];  // [k][m_loc]
  __shared__ __align__(16) unsigned short ADh[64][72], ADl[64][72];    // [n_loc][m_loc]
  int b = blockIdx.y, n0 = blockIdx.x * 64, z = blockIdx.z;
  int tid = threadIdx.x, wv = tid >> 6, l = tid & 63;
  int lr = l & 15, lk = l >> 4;
  int tk = tid >> 1, th = tid & 1;  // smT stager: row tk, 32-col half th
  int sn = tid >> 2, sq = tid & 3;  // adj stager
  const float* A = adj + (size_t)b * NN * NN;
  f32x4 zero = {0.f, 0.f, 0.f, 0.f};
  f32x4 acc[2][4];
#pragma unroll
  for (int i = 0; i < 2; ++i)
#pragma unroll
    for (int j = 0; j < 4; ++j) acc[i][j] = zero;
  float rsacc = 0.f;
  for (int m0 = z * (NN / MSPLIT); m0 < (z + 1) * (NN / MSPLIT); m0 += 64) {
    __syncthreads();
    {  // stage smT chunk [128][64] hi/lo: 32 shorts per thread per buffer
      const uint4* gh = (const uint4*)(smTh + ((size_t)b * NK + tk) * NN + m0 + th * 32);
      const uint4* gl = (const uint4*)(smTl + ((size_t)b * NK + tk) * NN + m0 + th * 32);
#pragma unroll
      for (int j = 0; j < 4; ++j) {
        *(uint4*)&STh[tk][th * 32 + j * 8] = gh[j];
        *(uint4*)&STl[tk][th * 32 + j * 8] = gl[j];
      }
    }
    {  // stage adj tile [64][64] fp32 -> bf16 hi/lo; fused row-sum
      const float* ap = A + (size_t)(n0 + sn) * NN + m0 + sq * 16;
      float ps = 0.f;
#pragma unroll
      for (int j = 0; j < 4; ++j) {
        float4 v = *(const float4*)(ap + j * 4);
        ushort4 vh, vl;
        split2(v.x, vh.x, vl.x);
        split2(v.y, vh.y, vl.y);
        split2(v.z, vh.z, vl.z);
        split2(v.w, vh.w, vl.w);
        *(ushort4*)&ADh[sn][sq * 16 + j * 4] = vh;
        *(ushort4*)&ADl[sn][sq * 16 + j * 4] = vl;
        ps += v.x + v.y + v.z + v.w;
      }
      ps += __shfl_xor(ps, 1, 64);
      ps += __shfl_xor(ps, 2, 64);
      rsacc += ps;
    }
    __syncthreads();
#pragma unroll
    for (int s = 0; s < 2; ++s) {
      bf16x8 ah0 = *(const bf16x8*)&STh[wv * 32 + lr][s * 32 + lk * 8];
      bf16x8 ah1 = *(const bf16x8*)&STh[wv * 32 + 16 + lr][s * 32 + lk * 8];
      bf16x8 al0 = *(const bf16x8*)&STl[wv * 32 + lr][s * 32 + lk * 8];
      bf16x8 al1 = *(const bf16x8*)&STl[wv * 32 + 16 + lr][s * 32 + lk * 8];
#pragma unroll
      for (int nt = 0; nt < 4; ++nt) {
        bf16x8 bh = *(const bf16x8*)&ADh[nt * 16 + lr][s * 32 + lk * 8];
        bf16x8 bl = *(const bf16x8*)&ADl[nt * 16 + lr][s * 32 + lk * 8];
        acc[0][nt] = MFMA(ah0, bh, acc[0][nt]);
        acc[0][nt] = MFMA(ah0, bl, acc[0][nt]);
        acc[0][nt] = MFMA(al0, bh, acc[0][nt]);
        acc[1][nt] = MFMA(ah1, bh, acc[1][nt]);
        acc[1][nt] = MFMA(ah1, bl, acc[1][nt]);
        acc[1][nt] = MFMA(al1, bh, acc[1][nt]);
      }
    }
  }
  float* Yb = Ytp + ((size_t)z * NB + b) * NK * NN;
#pragma unroll
  for (int kt = 0; kt < 2; ++kt)
#pragma unroll
    for (int nt = 0; nt < 4; ++nt)
#pragma unroll
      for (int reg = 0; reg < 4; ++reg) {
        int k = wv * 32 + kt * 16 + lk * 4 + reg;
        int n = n0 + nt * 16 + lr;
        Yb[(size_t)k * NN + n] = acc[kt][nt][reg];
      }
  if (sq == 0) dfp[((size_t)z * NB + b) * NN + n0 + sn] = rsacc;
}

// -------- out[b] = smT @ x_gathered  (K x F) via split-bf16 MFMA, k-split 2 --------
// grid (F/64, B, 2), 512 thr / 8 waves; wave: 16k x 32f; x transposed+split in LDS
__global__ __launch_bounds__(512) void k_feat(const unsigned short* __restrict__ smTh,
                                              const unsigned short* __restrict__ smTl,
                                              const float* __restrict__ x,
                                              const int* __restrict__ rowof,
                                              float* __restrict__ outf) {
  __shared__ __align__(16) unsigned short STh[64][72], STl[64][72];  // [k_loc][n_loc]
  __shared__ __align__(16) unsigned short XTh[64][72], XTl[64][72];  // [f_loc][n_loc]
  int b = blockIdx.y, fbase = blockIdx.x * 64, kh = blockIdx.z * 64;
  int tid = threadIdx.x, wv = tid >> 6, l = tid & 63;
  int lr = l & 15, lk = l >> 4;
  int wk = (wv >> 1) * 16, wf = (wv & 1) * 32;
  int tk = tid >> 3, tq = tid & 7;  // stagers: row tk/sn, 8-short octant
  f32x4 zero = {0.f, 0.f, 0.f, 0.f};
  f32x4 acc[2] = {zero, zero};
  for (int n0 = 0; n0 < NN; n0 += 64) {
    __syncthreads();
    {  // stage smT [64 k][64 n] hi/lo
      const uint4* gh = (const uint4*)(smTh + ((size_t)b * NK + kh + tk) * NN + n0 + tq * 8);
      const uint4* gl = (const uint4*)(smTl + ((size_t)b * NK + kh + tk) * NN + n0 + tq * 8);
      *(uint4*)&STh[tk][tq * 8] = gh[0];
      *(uint4*)&STl[tk][tq * 8] = gl[0];
    }
    {  // stage x tile transposed [64 f][64 n] hi/lo
      int ri = rowof[b * NN + n0 + tk];
      if (ri >= 0) {
        const float* xp = x + (size_t)ri * NF + fbase + tq * 8;
#pragma unroll
        for (int j = 0; j < 2; ++j) {
          float4 v = *(const float4*)(xp + j * 4);
          unsigned short h, lo;
          split2(v.x, h, lo); XTh[tq * 8 + j * 4 + 0][tk] = h; XTl[tq * 8 + j * 4 + 0][tk] = lo;
          split2(v.y, h, lo); XTh[tq * 8 + j * 4 + 1][tk] = h; XTl[tq * 8 + j * 4 + 1][tk] = lo;
          split2(v.z, h, lo); XTh[tq * 8 + j * 4 + 2][tk] = h; XTl[tq * 8 + j * 4 + 2][tk] = lo;
          split2(v.w, h, lo); XTh[tq * 8 + j * 4 + 3][tk] = h; XTl[tq * 8 + j * 4 + 3][tk] = lo;
        }
      } else {
#pragma unroll
        for (int e = 0; e < 8; ++e) {
          XTh[tq * 8 + e][tk] = 0;
          XTl[tq * 8 + e][tk] = 0;
        }
      }
    }
    __syncthreads();
#pragma unroll
    for (int s = 0; s < 2; ++s) {
      bf16x8 ah = *(const bf16x8*)&STh[wk + lr][s * 32 + lk * 8];
      bf16x8 al = *(const bf16x8*)&STl[wk + lr][s * 32 + lk * 8];
#pragma unroll
      for (int ft = 0; ft < 2; ++ft) {
        bf16x8 bh = *(const bf16x8*)&XTh[wf + ft * 16 + lr][s * 32 + lk * 8];
        bf16x8 bl = *(const bf16x8*)&XTl[wf + ft * 16 + lr][s * 32 + lk * 8];
        acc[ft] = MFMA(ah, bh, acc[ft]);
        acc[ft] = MFMA(ah, bl, acc[ft]);
        acc[ft] = MFMA(al, bh, acc[ft]);
      }
    }
  }
#pragma unroll
  for (int ft = 0; ft < 2; ++ft)
#pragma unroll
    for (int reg = 0; reg < 4; ++reg) {
      int kg = kh + wk + lk * 4 + reg;
      int fg = fbase + wf + ft * 16 + lr;
      outf[((size_t)b * NK + kg) * NF + fg] = acc[ft][reg];
    }
}

// -------- MFMA partials: padj[ch][b]=smT*Yt^T-chunk, pss[ch][b]=smT*sm-chunk --------
// grid (NCH, B, 2), 256 thr / 4 waves; dflat partials (dfp halves) fused in z=1
__global__ __launch_bounds__(256) void k_tt(const unsigned short* __restrict__ smTh,
                                            const unsigned short* __restrict__ smTl,
                                            const float* __restrict__ Ytp,
                                            const float* __restrict__ dfp,
                                            float* __restrict__ padj,
                                            float* __restrict__ pss,
                                            float* __restrict__ denp_arr) {
  __shared__ __align__(16) unsigned short STh[128][40], STl[128][40];  // [k][n_loc 32]
  __shared__ __align__(16) unsigned short YTh[128][40], YTl[128][40];
  __shared__ float red[256];
  int ch = blockIdx.x, b = blockIdx.y, z = blockIdx.z;
  int nbase = ch * 128;
  int tid = threadIdx.x, wv = tid >> 6, l = tid & 63;
  int lr = l & 15, lk = l >> 4;
  int tk = tid >> 1, th = tid & 1;
  f32x4 zero = {0.f, 0.f, 0.f, 0.f};
  f32x4 acc[2][8];
#pragma unroll
  for (int i = 0; i < 2; ++i)
#pragma unroll
    for (int j = 0; j < 8; ++j) acc[i][j] = zero;
  float denp = 0.f;
  for (int c = 0; c < 4; ++c) {
    int nn0 = nbase + c * 32;
    __syncthreads();
    {  // stage smT [128][32] hi/lo
      const unsigned short* gh = smTh + ((size_t)b * NK + tk) * NN + nn0 + th * 16;
      const unsigned short* gl = smTl + ((size_t)b * NK + tk) * NN + nn0 + th * 16;
#pragma unroll
      for (int j = 0; j < 4; ++j) {
        ushort4 hj = *(const ushort4*)(gh + j * 4);
        ushort4 lj = *(const ushort4*)(gl + j * 4);
        *(ushort4*)&STh[tk][th * 16 + j * 4] = hj;
        *(ushort4*)&STl[tk][th * 16 + j * 4] = lj;
        if (z) {  // fused mincut-den partial (each (k,n) elem once); dflat = dfp0+dfp1
          float4 da = *(const float4*)(dfp + (size_t)b * NN + nn0 + th * 16 + j * 4);
          float4 db = *(const float4*)(dfp + (size_t)(NB + b) * NN + nn0 + th * 16 + j * 4);
          float v0 = bf16f(hj.x) + bf16f(lj.x), v1 = bf16f(hj.y) + bf16f(lj.y);
          float v2 = bf16f(hj.z) + bf16f(lj.z), v3 = bf16f(hj.w) + bf16f(lj.w);
          denp += (da.x + db.x) * v0 * v0 + (da.y + db.y) * v1 * v1 +
                  (da.z + db.z) * v2 * v2 + (da.w + db.w) * v3 * v3;
        }
      }
    }
    if (!z) {  // stage Yt = Ytp0+Ytp1, fp32 -> bf16 hi/lo
      const float* y0 = Ytp + ((size_t)b * NK + tk) * NN + nn0 + th * 16;
      const float* y1 = y0 + (size_t)NB * NK * NN;
#pragma unroll
      for (int j = 0; j < 4; ++j) {
        float4 a = *(const float4*)(y0 + j * 4);
        float4 cc = *(const float4*)(y1 + j * 4);
        a.x += cc.x; a.y += cc.y; a.z += cc.z; a.w += cc.w;
        ushort4 vh, vl;
        split2(a.x, vh.x, vl.x);
        split2(a.y, vh.y, vl.y);
        split2(a.z, vh.z, vl.z);
        split2(a.w, vh.w, vl.w);
        *(ushort4*)&YTh[tk][th * 16 + j * 4] = vh;
        *(ushort4*)&YTl[tk][th * 16 + j * 4] = vl;
      }
    }
    __syncthreads();
    unsigned short(*Bh)[40] = z ? STh : YTh;
    unsigned short(*Bl)[40] = z ? STl : YTl;
    bf16x8 ah0 = *(const bf16x8*)&STh[wv * 32 + lr][lk * 8];
    bf16x8 ah1 = *(const bf16x8*)&STh[wv * 32 + 16 + lr][lk * 8];
    bf16x8 al0 = *(const bf16x8*)&STl[wv * 32 + lr][lk * 8];
    bf16x8 al1 = *(const bf16x8*)&STl[wv * 32 + 16 + lr][lk * 8];
#pragma unroll
    for (int ct = 0; ct < 8; ++ct) {
      bf16x8 bh = *(const bf16x8*)&Bh[ct * 16 + lr][lk * 8];
      bf16x8 bl = *(const bf16x8*)&Bl[ct * 16 + lr][lk * 8];
      acc[0][ct] = MFMA(ah0, bh, acc[0][ct]);
      acc[0][ct] = MFMA(ah0, bl, acc[0][ct]);
      acc[0][ct] = MFMA(al0, bh, acc[0][ct]);
      acc[1][ct] = MFMA(ah1, bh, acc[1][ct]);
      acc[1][ct] = MFMA(ah1, bl, acc[1][ct]);
      acc[1][ct] = MFMA(al1, bh, acc[1][ct]);
    }
  }
  float* O = (z ? pss : padj) + ((size_t)ch * NB + b) * NK * NK;
#pragma unroll
  for (int kt = 0; kt < 2; ++kt)
#pragma unroll
    for (int ct = 0; ct < 8; ++ct)
#pragma unroll
      for (int reg = 0; reg < 4; ++reg)
        O[(size_t)(wv * 32 + kt * 16 + lk * 4 + reg) * NK + ct * 16 + lr] =
            acc[kt][ct][reg];
  if (z) {
    red[tid] = denp;
    __syncthreads();
#pragma unroll
    for (int sft = 128; sft; sft >>= 1) {
      if (tid < sft) red[tid] += red[tid + sft];
      __syncthreads();
    }
    if (tid == 0) denp_arr[ch * NB + b] = red[0];
  }
}

// -------- sum the NCH partials into adjraw(->out_adj region) / ssb --------
__global__ __launch_bounds__(256) void k_reduce(const float* __restrict__ padj,
                                                const float* __restrict__ pss,
                                                float* __restrict__ adjraw,
                                                float* __restrict__ ssb) {
  size_t i = (size_t)blockIdx.x * 256 + threadIdx.x;
  size_t stride4 = (size_t)NB * NK * NK / 4;
  const float4* pa = (const float4*)padj + i;
  const float4* ps = (const float4*)pss + i;
  float4 a = make_float4(0.f, 0.f, 0.f, 0.f);
  float4 s = make_float4(0.f, 0.f, 0.f, 0.f);
#pragma unroll
  for (int ch = 0; ch < NCH; ++ch) {
    float4 va = pa[(size_t)ch * stride4];
    float4 vs = ps[(size_t)ch * stride4];
    a.x += va.x; a.y += va.y; a.z += va.z; a.w += va.w;
    s.x += vs.x; s.y += vs.y; s.z += vs.z; s.w += vs.w;
  }
  ((float4*)adjraw)[i] = a;
  ((float4*)ssb)[i] = s;
}

__device__ __forceinline__ float block_reduce_sum(float v, float* red) {
  int tid = threadIdx.x;
  red[tid] = v;
  __syncthreads();
#pragma unroll
  for (int sft = 128; sft; sft >>= 1) {
    if (tid < sft) red[tid] += red[tid + sft];
    __syncthreads();
  }
  float r = red[0];
  __syncthreads();
  return r;
}

// -------- per-batch epilogue (in-place on out_adj holding adjraw) --------
__global__ __launch_bounds__(256) void k_finalize(const float* __restrict__ denp_arr,
                                                  const float* __restrict__ ssb,
                                                  float* __restrict__ out_adj,
                                                  float* __restrict__ out_loss) {
  __shared__ float red[256];
  __shared__ float sd[NK];
  int b = blockIdx.x, tid = threadIdx.x;
  float* AR = out_adj + (size_t)b * NK * NK;
  const float* SS = ssb + (size_t)b * NK * NK;

  float tv = (tid < NK) ? AR[tid * NK + tid] : 0.f;
  float trace = block_reduce_sum(tv, red);
  float den = 0.f;
#pragma unroll
  for (int ch = 0; ch < NCH; ++ch) den += denp_arr[ch * NB + b];

  float n2 = 0.f;
  for (int i4 = tid; i4 < NK * NK / 4; i4 += 256) {
    float4 v = *(const float4*)(SS + (size_t)i4 * 4);
    n2 += v.x * v.x + v.y * v.y + v.z * v.z + v.w * v.w;
  }
  float nrm = sqrtf(block_reduce_sum(n2, red));

  const float isk = 0.08838834764831845f;  // 1/sqrt(128)
  float osum = 0.f;
  for (int i = tid; i < NK * NK; i += 256) {
    int r = i >> 7, c = i & (NK - 1);
    float val = SS[i] / nrm - ((r == c) ? isk : 0.f);
    osum += val * val;
  }
  float ortho = sqrtf(block_reduce_sum(osum, red));

  if (tid < NK) {
    float rsumv = 0.f;
    const float* row = AR + (size_t)tid * NK;
    for (int j = 0; j < NK; ++j) rsumv += (j == tid) ? 0.f : row[j];
    sd[tid] = sqrtf(rsumv) + EPSV;
  }
  __syncthreads();

  for (int i = tid; i < NK * NK; i += 256) {
    int r = i >> 7, c = i & (NK - 1);
    AR[i] = (r == c) ? 0.f : AR[i] / (sd[r] * sd[c]);
  }

  if (tid == 0) {
    atomicAdd(&out_loss[0], -(trace / den) * (1.0f / NB));
    atomicAdd(&out_loss[1], ortho * (1.0f / NB));
  }
}

extern "C" void kernel_launch(void* const* d_in, const int* in_sizes, int n_in,
                              void* d_out, int out_size, void* d_ws, size_t ws_size,
                              hipStream_t stream) {
  const float* x = (const float*)d_in[0];
  const float* s = (const float*)d_in[1];
  const float* adj = (const float*)d_in[2];
  const int* fidx = (const int*)d_in[3];
  int T = in_sizes[3];

  // output layout: sm | out | out_adj | mincut_loss | ortho_loss
  float* out_sm = (float*)d_out;
  float* out_feat = out_sm + (size_t)NB * NN * NK;
  float* out_adj = out_feat + (size_t)NB * NK * NF;
  float* out_loss = out_adj + (size_t)NB * NK * NK;

  // workspace (~42 MB)
  float* Ytp = (float*)d_ws;                            // 2*B*K*N fp32
  float* dfp = Ytp + (size_t)2 * NB * NK * NN;          // 2*B*N
  float* padj = dfp + (size_t)2 * NB * NN;              // NCH*B*K*K
  float* pss = padj + (size_t)NCH * NB * NK * NK;       // NCH*B*K*K
  float* ssb = pss + (size_t)NCH * NB * NK * NK;        // B*K*K
  float* denp = ssb + (size_t)NB * NK * NK;             // NCH*B
  unsigned short* smTh = (unsigned short*)(denp + NCH * NB);  // B*K*N bf16
  unsigned short* smTl = smTh + (size_t)NB * NK * NN;         // B*K*N bf16
  int* rowof = (int*)(smTl + (size_t)NB * NK * NN);           // B*N ints

  hipMemsetAsync(out_loss, 0, 2 * sizeof(float), stream);

  k_softmax<<<NB * NN / 64, 256, 0, stream>>>(s, fidx, T, out_sm, smTh, smTl, rowof);
  k_adj_sm<<<dim3(NN / 64, NB, MSPLIT), 256, 0, stream>>>(adj, smTh, smTl, Ytp, dfp);
  k_feat<<<dim3(NF / 64, NB, 2), 512, 0, stream>>>(smTh, smTl, x, rowof, out_feat);
  k_tt<<<dim3(NCH, NB, 2), 256, 0, stream>>>(smTh, smTl, Ytp, dfp, padj, pss, denp);
  k_reduce<<<NB * NK * NK / 4 / 256, 256, 0, stream>>>(padj, pss, out_adj, ssb);
  k_finalize<<<NB, 256, 0, stream>>>(denp, ssb, out_adj, out_loss);
}

// Round 9
// 240.632 us; speedup vs baseline: 1.8799x; 1.0528x over previous
//
#include <hip/hip_runtime.h>

constexpr int NB = 16, NN = 1024, NF = 512, NK = 128;
constexpr int NCH = 8;     // k_tt n-chunks (128 rows each)
constexpr int MSPLIT = 2;  // k_adj_sm reduction split
constexpr float EPSV = 1e-15f;

typedef __attribute__((ext_vector_type(8))) short bf16x8;
typedef __attribute__((ext_vector_type(4))) float f32x4;

__device__ __forceinline__ f32x4 MFMA(bf16x8 a, bf16x8 b, f32x4 c) {
  return __builtin_amdgcn_mfma_f32_16x16x32_bf16(a, b, c, 0, 0, 0);
}

__device__ __forceinline__ unsigned short bf16_rn(float f) {
  unsigned int u = __float_as_uint(f);
  u += 0x7fffu + ((u >> 16) & 1u);
  return (unsigned short)(u >> 16);
}
__device__ __forceinline__ float bf16f(unsigned short h) {
  return __uint_as_float((unsigned int)h << 16);
}
__device__ __forceinline__ void split2(float f, unsigned short& h, unsigned short& lo) {
  h = bf16_rn(f);
  lo = bf16_rn(f - bf16f(h));
}

// -------- softmax + fp32 sm + bf16 hi/lo smT + gathered/transposed bf16 xT --------
// valid rows of graph b are t = start_b + n (flat_index consecutive per batch)
// grid (B*N/64), 256 threads; block = 64 rows of one b
__global__ __launch_bounds__(256) void k_softmax(const float* __restrict__ s,
                                                 const float* __restrict__ x,
                                                 const int* __restrict__ fidx, int T,
                                                 float* __restrict__ sm,
                                                 unsigned short* __restrict__ smTh,
                                                 unsigned short* __restrict__ smTl,
                                                 unsigned short* __restrict__ xTh) {
  __shared__ float P[64][129];
  __shared__ float XF[64][65];
  __shared__ int sh_start, sh_cnt;
  int blk = blockIdx.x;
  int b = blk >> 4, n0 = (blk & 15) * 64;
  int tid = threadIdx.x, wv = tid >> 6, lane = tid & 63;
  if (tid == 0) {
    int lo = 0, hi = T, tgt = b * NN;
    while (lo < hi) { int m = (lo + hi) >> 1; if (fidx[m] < tgt) lo = m + 1; else hi = m; }
    sh_start = lo;
    int lo2 = lo, hi2 = T, tgt2 = b * NN + NN;
    while (lo2 < hi2) { int m = (lo2 + hi2) >> 1; if (fidx[m] < tgt2) lo2 = m + 1; else hi2 = m; }
    sh_cnt = lo2 - lo;
  }
  __syncthreads();
  int start = sh_start, cnt = sh_cnt;
  // phase 1: softmax, each wave does 16 rows
  for (int i = 0; i < 16; ++i) {
    int r = wv * 16 + i;
    float e0 = 0.f, e1 = 0.f;
    if (n0 + r < cnt) {
      const float* row = s + (size_t)(start + n0 + r) * NK;
      float a = row[lane], c = row[lane + 64];
      float m = fmaxf(a, c);
#pragma unroll
      for (int off = 32; off; off >>= 1) m = fmaxf(m, __shfl_xor(m, off, 64));
      e0 = expf(a - m);
      e1 = expf(c - m);
      float sum = e0 + e1;
#pragma unroll
      for (int off = 32; off; off >>= 1) sum += __shfl_xor(sum, off, 64);
      float inv = 1.0f / sum;
      e0 *= inv;
      e1 *= inv;
    }
    P[r][lane] = e0;
    P[r][lane + 64] = e1;
  }
  __syncthreads();
  // phase 2a: fp32 sm, coalesced float4 stores
  int r2 = tid >> 2, cb = (tid & 3) * 32;
  float* orow = sm + ((size_t)b * NN + n0 + r2) * NK + cb;
#pragma unroll
  for (int j = 0; j < 8; ++j) {
    float4 v = make_float4(P[r2][cb + j * 4], P[r2][cb + j * 4 + 1],
                           P[r2][cb + j * 4 + 2], P[r2][cb + j * 4 + 3]);
    *(float4*)(orow + j * 4) = v;
  }
  // phase 2b: transposed bf16 hi/lo; wave wv covers k in [wv*32, wv*32+32)
  for (int j = 0; j < 32; ++j) {
    int k = wv * 32 + j;
    float v = P[lane][k];
    unsigned short h, lo;
    split2(v, h, lo);
    size_t off = ((size_t)b * NK + k) * NN + n0 + lane;
    smTh[off] = h;
    smTl[off] = lo;
  }
  // phase 3: x gather+transpose -> xTh[b][f][n], bf16 hi only, 8 chunks of 64 f
  int lrw = tid >> 2, f4 = tid & 3;          // load: row lrw, 16-float quarter f4
  bool valid = (n0 + lrw) < cnt;
  int gg = tid & 7;                          // write: 8-elem n-group
  for (int fc = 0; fc < 8; ++fc) {
    __syncthreads();
    const float* xp = x + (size_t)(start + n0 + lrw) * NF + fc * 64 + f4 * 16;
#pragma unroll
    for (int j = 0; j < 4; ++j) {
      float4 v = valid ? *(const float4*)(xp + j * 4) : make_float4(0.f, 0.f, 0.f, 0.f);
      XF[lrw][f4 * 16 + j * 4 + 0] = v.x;
      XF[lrw][f4 * 16 + j * 4 + 1] = v.y;
      XF[lrw][f4 * 16 + j * 4 + 2] = v.z;
      XF[lrw][f4 * 16 + j * 4 + 3] = v.w;
    }
    __syncthreads();
#pragma unroll
    for (int p = 0; p < 2; ++p) {
      int fl = p * 32 + (tid >> 3);
      unsigned short hh[8];
#pragma unroll
      for (int e = 0; e < 8; ++e) hh[e] = bf16_rn(XF[gg * 8 + e][fl]);
      size_t off = ((size_t)b * NF + fc * 64 + fl) * NN + n0 + gg * 8;
      *(uint4*)(xTh + off) = *(uint4*)hh;
    }
  }
}

// -------- Yt[k][n] = sum_m sm[m][k]*adj[m][n]  (adj symmetric => = Y[n][k]) --------
// grid (N/64, B, MSPLIT), 256 thr / 4 waves
__global__ __launch_bounds__(256) void k_adj_sm(const float* __restrict__ adj,
                                                const unsigned short* __restrict__ smTh,
                                                const unsigned short* __restrict__ smTl,
                                                float* __restrict__ Ytp,
                                                float* __restrict__ dfp) {
  __shared__ __align__(16) unsigned short STh[128][72], STl[128][72];  // [k][m_loc]
  __shared__ __align__(16) unsigned short ADh[64][72], ADl[64][72];    // [n_loc][m_loc]
  int b = blockIdx.y, n0 = blockIdx.x * 64, z = blockIdx.z;
  int tid = threadIdx.x, wv = tid >> 6, l = tid & 63;
  int lr = l & 15, lk = l >> 4;
  int tk = tid >> 1, th = tid & 1;  // smT stager: row tk, 32-col half th
  int sn = tid >> 2, sq = tid & 3;  // adj stager
  const float* A = adj + (size_t)b * NN * NN;
  f32x4 zero = {0.f, 0.f, 0.f, 0.f};
  f32x4 acc[2][4];
#pragma unroll
  for (int i = 0; i < 2; ++i)
#pragma unroll
    for (int j = 0; j < 4; ++j) acc[i][j] = zero;
  float rsacc = 0.f;
  for (int m0 = z * (NN / MSPLIT); m0 < (z + 1) * (NN / MSPLIT); m0 += 64) {
    __syncthreads();
    {  // stage smT chunk [128][64] hi/lo: 32 shorts per thread per buffer
      const uint4* gh = (const uint4*)(smTh + ((size_t)b * NK + tk) * NN + m0 + th * 32);
      const uint4* gl = (const uint4*)(smTl + ((size_t)b * NK + tk) * NN + m0 + th * 32);
#pragma unroll
      for (int j = 0; j < 4; ++j) {
        *(uint4*)&STh[tk][th * 32 + j * 8] = gh[j];
        *(uint4*)&STl[tk][th * 32 + j * 8] = gl[j];
      }
    }
    {  // stage adj tile [64][64] fp32 -> bf16 hi/lo; fused row-sum
      const float* ap = A + (size_t)(n0 + sn) * NN + m0 + sq * 16;
      float ps = 0.f;
#pragma unroll
      for (int j = 0; j < 4; ++j) {
        float4 v = *(const float4*)(ap + j * 4);
        ushort4 vh, vl;
        split2(v.x, vh.x, vl.x);
        split2(v.y, vh.y, vl.y);
        split2(v.z, vh.z, vl.z);
        split2(v.w, vh.w, vl.w);
        *(ushort4*)&ADh[sn][sq * 16 + j * 4] = vh;
        *(ushort4*)&ADl[sn][sq * 16 + j * 4] = vl;
        ps += v.x + v.y + v.z + v.w;
      }
      ps += __shfl_xor(ps, 1, 64);
      ps += __shfl_xor(ps, 2, 64);
      rsacc += ps;
    }
    __syncthreads();
#pragma unroll
    for (int s = 0; s < 2; ++s) {
      bf16x8 ah0 = *(const bf16x8*)&STh[wv * 32 + lr][s * 32 + lk * 8];
      bf16x8 ah1 = *(const bf16x8*)&STh[wv * 32 + 16 + lr][s * 32 + lk * 8];
      bf16x8 al0 = *(const bf16x8*)&STl[wv * 32 + lr][s * 32 + lk * 8];
      bf16x8 al1 = *(const bf16x8*)&STl[wv * 32 + 16 + lr][s * 32 + lk * 8];
#pragma unroll
      for (int nt = 0; nt < 4; ++nt) {
        bf16x8 bh = *(const bf16x8*)&ADh[nt * 16 + lr][s * 32 + lk * 8];
        bf16x8 bl = *(const bf16x8*)&ADl[nt * 16 + lr][s * 32 + lk * 8];
        acc[0][nt] = MFMA(ah0, bh, acc[0][nt]);
        acc[0][nt] = MFMA(ah0, bl, acc[0][nt]);
        acc[0][nt] = MFMA(al0, bh, acc[0][nt]);
        acc[1][nt] = MFMA(ah1, bh, acc[1][nt]);
        acc[1][nt] = MFMA(ah1, bl, acc[1][nt]);
        acc[1][nt] = MFMA(al1, bh, acc[1][nt]);
      }
    }
  }
  float* Yb = Ytp + ((size_t)z * NB + b) * NK * NN;
#pragma unroll
  for (int kt = 0; kt < 2; ++kt)
#pragma unroll
    for (int nt = 0; nt < 4; ++nt)
#pragma unroll
      for (int reg = 0; reg < 4; ++reg) {
        int k = wv * 32 + kt * 16 + lk * 4 + reg;
        int n = n0 + nt * 16 + lr;
        Yb[(size_t)k * NN + n] = acc[kt][nt][reg];
      }
  if (sq == 0) dfp[((size_t)z * NB + b) * NN + n0 + sn] = rsacc;
}

// -------- out[b] = smT @ x  (K x F) via MFMA; both operands pre-transposed --------
// grid (F/64, B, 2), 512 thr / 8 waves; all staging = vectorized uint4 row copies
__global__ __launch_bounds__(512) void k_feat(const unsigned short* __restrict__ smTh,
                                              const unsigned short* __restrict__ smTl,
                                              const unsigned short* __restrict__ xTh,
                                              float* __restrict__ outf) {
  __shared__ __align__(16) unsigned short STh[64][72], STl[64][72];  // [k_loc][n_loc]
  __shared__ __align__(16) unsigned short XT[64][72];                // [f_loc][n_loc]
  int b = blockIdx.y, fbase = blockIdx.x * 64, kh = blockIdx.z * 64;
  int tid = threadIdx.x, wv = tid >> 6, l = tid & 63;
  int lr = l & 15, lk = l >> 4;
  int wk = (wv >> 1) * 16, wf = (wv & 1) * 32;
  int tk = tid >> 3, tq = tid & 7;
  f32x4 zero = {0.f, 0.f, 0.f, 0.f};
  f32x4 acc[2] = {zero, zero};
  for (int n0 = 0; n0 < NN; n0 += 64) {
    __syncthreads();
    size_t so = ((size_t)b * NK + kh + tk) * NN + n0 + tq * 8;
    *(uint4*)&STh[tk][tq * 8] = *(const uint4*)(smTh + so);
    *(uint4*)&STl[tk][tq * 8] = *(const uint4*)(smTl + so);
    size_t xo = ((size_t)b * NF + fbase + tk) * NN + n0 + tq * 8;
    *(uint4*)&XT[tk][tq * 8] = *(const uint4*)(xTh + xo);
    __syncthreads();
#pragma unroll
    for (int s = 0; s < 2; ++s) {
      bf16x8 ah = *(const bf16x8*)&STh[wk + lr][s * 32 + lk * 8];
      bf16x8 al = *(const bf16x8*)&STl[wk + lr][s * 32 + lk * 8];
#pragma unroll
      for (int ft = 0; ft < 2; ++ft) {
        bf16x8 bh = *(const bf16x8*)&XT[wf + ft * 16 + lr][s * 32 + lk * 8];
        acc[ft] = MFMA(ah, bh, acc[ft]);
        acc[ft] = MFMA(al, bh, acc[ft]);
      }
    }
  }
#pragma unroll
  for (int ft = 0; ft < 2; ++ft)
#pragma unroll
    for (int reg = 0; reg < 4; ++reg) {
      int kg = kh + wk + lk * 4 + reg;
      int fg = fbase + wf + ft * 16 + lr;
      outf[((size_t)b * NK + kg) * NF + fg] = acc[ft][reg];
    }
}

// -------- MFMA partials: padj[ch][b]=smT*Yt^T-chunk, pss[ch][b]=smT*sm-chunk --------
// grid (NCH, B, 2), 256 thr / 4 waves; dflat partials (dfp halves) fused in z=1
__global__ __launch_bounds__(256) void k_tt(const unsigned short* __restrict__ smTh,
                                            const unsigned short* __restrict__ smTl,
                                            const float* __restrict__ Ytp,
                                            const float* __restrict__ dfp,
                                            float* __restrict__ padj,
                                            float* __restrict__ pss,
                                            float* __restrict__ denp_arr) {
  __shared__ __align__(16) unsigned short STh[128][40], STl[128][40];  // [k][n_loc 32]
  __shared__ __align__(16) unsigned short YTh[128][40], YTl[128][40];
  __shared__ float red[256];
  int ch = blockIdx.x, b = blockIdx.y, z = blockIdx.z;
  int nbase = ch * 128;
  int tid = threadIdx.x, wv = tid >> 6, l = tid & 63;
  int lr = l & 15, lk = l >> 4;
  int tk = tid >> 1, th = tid & 1;
  f32x4 zero = {0.f, 0.f, 0.f, 0.f};
  f32x4 acc[2][8];
#pragma unroll
  for (int i = 0; i < 2; ++i)
#pragma unroll
    for (int j = 0; j < 8; ++j) acc[i][j] = zero;
  float denp = 0.f;
  for (int c = 0; c < 4; ++c) {
    int nn0 = nbase + c * 32;
    __syncthreads();
    {  // stage smT [128][32] hi/lo
      const unsigned short* gh = smTh + ((size_t)b * NK + tk) * NN + nn0 + th * 16;
      const unsigned short* gl = smTl + ((size_t)b * NK + tk) * NN + nn0 + th * 16;
#pragma unroll
      for (int j = 0; j < 4; ++j) {
        ushort4 hj = *(const ushort4*)(gh + j * 4);
        ushort4 lj = *(const ushort4*)(gl + j * 4);
        *(ushort4*)&STh[tk][th * 16 + j * 4] = hj;
        *(ushort4*)&STl[tk][th * 16 + j * 4] = lj;
        if (z) {  // fused mincut-den partial (each (k,n) elem once); dflat = dfp0+dfp1
          float4 da = *(const float4*)(dfp + (size_t)b * NN + nn0 + th * 16 + j * 4);
          float4 db = *(const float4*)(dfp + (size_t)(NB + b) * NN + nn0 + th * 16 + j * 4);
          float v0 = bf16f(hj.x) + bf16f(lj.x), v1 = bf16f(hj.y) + bf16f(lj.y);
          float v2 = bf16f(hj.z) + bf16f(lj.z), v3 = bf16f(hj.w) + bf16f(lj.w);
          denp += (da.x + db.x) * v0 * v0 + (da.y + db.y) * v1 * v1 +
                  (da.z + db.z) * v2 * v2 + (da.w + db.w) * v3 * v3;
        }
      }
    }
    if (!z) {  // stage Yt = Ytp0+Ytp1, fp32 -> bf16 hi/lo
      const float* y0 = Ytp + ((size_t)b * NK + tk) * NN + nn0 + th * 16;
      const float* y1 = y0 + (size_t)NB * NK * NN;
#pragma unroll
      for (int j = 0; j < 4; ++j) {
        float4 a = *(const float4*)(y0 + j * 4);
        float4 cc = *(const float4*)(y1 + j * 4);
        a.x += cc.x; a.y += cc.y; a.z += cc.z; a.w += cc.w;
        ushort4 vh, vl;
        split2(a.x, vh.x, vl.x);
        split2(a.y, vh.y, vl.y);
        split2(a.z, vh.z, vl.z);
        split2(a.w, vh.w, vl.w);
        *(ushort4*)&YTh[tk][th * 16 + j * 4] = vh;
        *(ushort4*)&YTl[tk][th * 16 + j * 4] = vl;
      }
    }
    __syncthreads();
    unsigned short(*Bh)[40] = z ? STh : YTh;
    unsigned short(*Bl)[40] = z ? STl : YTl;
    bf16x8 ah0 = *(const bf16x8*)&STh[wv * 32 + lr][lk * 8];
    bf16x8 ah1 = *(const bf16x8*)&STh[wv * 32 + 16 + lr][lk * 8];
    bf16x8 al0 = *(const bf16x8*)&STl[wv * 32 + lr][lk * 8];
    bf16x8 al1 = *(const bf16x8*)&STl[wv * 32 + 16 + lr][lk * 8];
#pragma unroll
    for (int ct = 0; ct < 8; ++ct) {
      bf16x8 bh = *(const bf16x8*)&Bh[ct * 16 + lr][lk * 8];
      bf16x8 bl = *(const bf16x8*)&Bl[ct * 16 + lr][lk * 8];
      acc[0][ct] = MFMA(ah0, bh, acc[0][ct]);
      acc[0][ct] = MFMA(ah0, bl, acc[0][ct]);
      acc[0][ct] = MFMA(al0, bh, acc[0][ct]);
      acc[1][ct] = MFMA(ah1, bh, acc[1][ct]);
      acc[1][ct] = MFMA(ah1, bl, acc[1][ct]);
      acc[1][ct] = MFMA(al1, bh, acc[1][ct]);
    }
  }
  float* O = (z ? pss : padj) + ((size_t)ch * NB + b) * NK * NK;
#pragma unroll
  for (int kt = 0; kt < 2; ++kt)
#pragma unroll
    for (int ct = 0; ct < 8; ++ct)
#pragma unroll
      for (int reg = 0; reg < 4; ++reg)
        O[(size_t)(wv * 32 + kt * 16 + lk * 4 + reg) * NK + ct * 16 + lr] =
            acc[kt][ct][reg];
  if (z) {
    red[tid] = denp;
    __syncthreads();
#pragma unroll
    for (int sft = 128; sft; sft >>= 1) {
      if (tid < sft) red[tid] += red[tid + sft];
      __syncthreads();
    }
    if (tid == 0) denp_arr[ch * NB + b] = red[0];
  }
}

// -------- sum the NCH partials into adjraw(->out_adj region) / ssb; zero loss --------
__global__ __launch_bounds__(256) void k_reduce(const float* __restrict__ padj,
                                                const float* __restrict__ pss,
                                                float* __restrict__ adjraw,
                                                float* __restrict__ ssb,
                                                float* __restrict__ out_loss) {
  if (blockIdx.x == 0 && threadIdx.x < 2) out_loss[threadIdx.x] = 0.f;
  size_t i = (size_t)blockIdx.x * 256 + threadIdx.x;
  size_t stride4 = (size_t)NB * NK * NK / 4;
  const float4* pa = (const float4*)padj + i;
  const float4* ps = (const float4*)pss + i;
  float4 a = make_float4(0.f, 0.f, 0.f, 0.f);
  float4 s = make_float4(0.f, 0.f, 0.f, 0.f);
#pragma unroll
  for (int ch = 0; ch < NCH; ++ch) {
    float4 va = pa[(size_t)ch * stride4];
    float4 vs = ps[(size_t)ch * stride4];
    a.x += va.x; a.y += va.y; a.z += va.z; a.w += va.w;
    s.x += vs.x; s.y += vs.y; s.z += vs.z; s.w += vs.w;
  }
  ((float4*)adjraw)[i] = a;
  ((float4*)ssb)[i] = s;
}

__device__ __forceinline__ float block_reduce_sum(float v, float* red) {
  int tid = threadIdx.x;
  red[tid] = v;
  __syncthreads();
#pragma unroll
  for (int sft = 128; sft; sft >>= 1) {
    if (tid < sft) red[tid] += red[tid + sft];
    __syncthreads();
  }
  float r = red[0];
  __syncthreads();
  return r;
}

// -------- per-batch epilogue (in-place on out_adj holding adjraw) --------
__global__ __launch_bounds__(256) void k_finalize(const float* __restrict__ denp_arr,
                                                  const float* __restrict__ ssb,
                                                  float* __restrict__ out_adj,
                                                  float* __restrict__ out_loss) {
  __shared__ float red[256];
  __shared__ float sd[NK];
  int b = blockIdx.x, tid = threadIdx.x;
  float* AR = out_adj + (size_t)b * NK * NK;
  const float* SS = ssb + (size_t)b * NK * NK;

  float tv = (tid < NK) ? AR[tid * NK + tid] : 0.f;
  float trace = block_reduce_sum(tv, red);
  float den = 0.f;
#pragma unroll
  for (int ch = 0; ch < NCH; ++ch) den += denp_arr[ch * NB + b];

  float n2 = 0.f;
  for (int i4 = tid; i4 < NK * NK / 4; i4 += 256) {
    float4 v = *(const float4*)(SS + (size_t)i4 * 4);
    n2 += v.x * v.x + v.y * v.y + v.z * v.z + v.w * v.w;
  }
  float nrm = sqrtf(block_reduce_sum(n2, red));

  const float isk = 0.08838834764831845f;  // 1/sqrt(128)
  float osum = 0.f;
  for (int i = tid; i < NK * NK; i += 256) {
    int r = i >> 7, c = i & (NK - 1);
    float val = SS[i] / nrm - ((r == c) ? isk : 0.f);
    osum += val * val;
  }
  float ortho = sqrtf(block_reduce_sum(osum, red));

  if (tid < NK) {
    float rsumv = 0.f;
    const float* row = AR + (size_t)tid * NK;
    for (int j = 0; j < NK; ++j) rsumv += (j == tid) ? 0.f : row[j];
    sd[tid] = sqrtf(rsumv) + EPSV;
  }
  __syncthreads();

  for (int i = tid; i < NK * NK; i += 256) {
    int r = i >> 7, c = i & (NK - 1);
    AR[i] = (r == c) ? 0.f : AR[i] / (sd[r] * sd[c]);
  }

  if (tid == 0) {
    atomicAdd(&out_loss[0], -(trace / den) * (1.0f / NB));
    atomicAdd(&out_loss[1], ortho * (1.0f / NB));
  }
}

extern "C" void kernel_launch(void* const* d_in, const int* in_sizes, int n_in,
                              void* d_out, int out_size, void* d_ws, size_t ws_size,
                              hipStream_t stream) {
  const float* x = (const float*)d_in[0];
  const float* s = (const float*)d_in[1];
  const float* adj = (const float*)d_in[2];
  const int* fidx = (const int*)d_in[3];
  int T = in_sizes[3];

  // output layout: sm | out | out_adj | mincut_loss | ortho_loss
  float* out_sm = (float*)d_out;
  float* out_feat = out_sm + (size_t)NB * NN * NK;
  float* out_adj = out_feat + (size_t)NB * NK * NF;
  float* out_loss = out_adj + (size_t)NB * NK * NK;

  // workspace (~57 MB)
  float* Ytp = (float*)d_ws;                            // 2*B*K*N fp32
  float* dfp = Ytp + (size_t)2 * NB * NK * NN;          // 2*B*N
  float* padj = dfp + (size_t)2 * NB * NN;              // NCH*B*K*K
  float* pss = padj + (size_t)NCH * NB * NK * NK;       // NCH*B*K*K
  float* ssb = pss + (size_t)NCH * NB * NK * NK;        // B*K*K
  float* denp = ssb + (size_t)NB * NK * NK;             // NCH*B
  unsigned short* smTh = (unsigned short*)(denp + NCH * NB);  // B*K*N bf16
  unsigned short* smTl = smTh + (size_t)NB * NK * NN;         // B*K*N bf16
  unsigned short* xTh = smTl + (size_t)NB * NK * NN;          // B*F*N bf16

  k_softmax<<<NB * NN / 64, 256, 0, stream>>>(s, x, fidx, T, out_sm, smTh, smTl, xTh);
  k_adj_sm<<<dim3(NN / 64, NB, MSPLIT), 256, 0, stream>>>(adj, smTh, smTl, Ytp, dfp);
  k_feat<<<dim3(NF / 64, NB, 2), 512, 0, stream>>>(smTh, smTl, xTh, out_feat);
  k_tt<<<dim3(NCH, NB, 2), 256, 0, stream>>>(smTh, smTl, Ytp, dfp, padj, pss, denp);
  k_reduce<<<NB * NK * NK / 4 / 256, 256, 0, stream>>>(padj, pss, out_adj, ssb, out_loss);
  k_finalize<<<NB, 256, 0, stream>>>(denp, ssb, out_adj, out_loss);
}